// Round 1
// baseline (34280.444 us; speedup 1.0000x reference)
//
#include <hip/hip_runtime.h>
#include <hip/hip_cooperative_groups.h>
#include <math.h>

namespace cg = cooperative_groups;

// ---------------- problem dims ----------------
#define T_STEPS 512
#define BATCH   128
#define DIN     256
#define HMAIN   1024
#define HHYP    256
#define OUTN    128
#define EPS     1e-3f

#define KSPLIT_NONE (1<<30)

typedef __attribute__((ext_vector_type(4))) float f32x4;
typedef __attribute__((ext_vector_type(8))) short s16x8;

__device__ __forceinline__ float sigm(float x){ return 1.f/(1.f + expf(-x)); }

__device__ __forceinline__ unsigned short f2bf(float f){
    union { float f; unsigned u; } x; x.f = f;
    unsigned r = x.u + 0x7FFFu + ((x.u >> 16) & 1u);   // RNE
    return (unsigned short)(r >> 16);
}

// =====================================================================
// fp32 tiled GEMM (prep only): tile 32x64, KT=32, 128 thr, 4x4 micro
// =====================================================================
#define BM 32
#define BN 64
#define KT 32
__device__ void gemm_dev(const float* __restrict__ A1, int lda1, int ksplit,
                         const float* __restrict__ A2, int lda2,
                         const float* __restrict__ Bp, int ldb, int b_nk,
                         const float* __restrict__ bias,
                         float* __restrict__ C, int ldc,
                         int K, int k0, int mtile, int ntile)
{
    __shared__ __align__(16) float As[KT][BM+4];
    __shared__ __align__(16) float Bs[KT][BN+4];
    const int tid = threadIdx.x;
    const int mt = tid >> 4, nt = tid & 15;
    const int m0g = mtile*BM, n0g = ntile*BN;
    float acc[4][4];
    #pragma unroll
    for (int i=0;i<4;++i) { acc[i][0]=0;acc[i][1]=0;acc[i][2]=0;acc[i][3]=0; }
    for (int kt = 0; kt < K; kt += KT) {
        __syncthreads();
        #pragma unroll
        for (int i=0;i<8;++i){
            int e = tid + i*128;
            int m = e >> 5, k = e & 31;
            int gk = k0 + kt + k, gm = m0g + m;
            float v = (gk < ksplit) ? A1[(size_t)gm*lda1 + gk]
                                    : A2[(size_t)gm*lda2 + (gk - ksplit)];
            As[k][m] = v;
        }
        if (b_nk) {
            #pragma unroll
            for (int i=0;i<16;++i){
                int e = tid + i*128;
                int n = e >> 5, k = e & 31;
                Bs[k][n] = Bp[(size_t)(n0g + n)*ldb + (k0 + kt + k)];
            }
        } else {
            #pragma unroll
            for (int i=0;i<16;++i){
                int e = tid + i*128;
                int k = e >> 6, n = e & 63;
                Bs[k][n] = Bp[(size_t)(k0 + kt + k)*ldb + (n0g + n)];
            }
        }
        __syncthreads();
        #pragma unroll
        for (int k=0;k<KT;++k){
            float4 av = *(const float4*)(&As[k][4*mt]);
            float4 bv = *(const float4*)(&Bs[k][4*nt]);
            acc[0][0]+=av.x*bv.x; acc[0][1]+=av.x*bv.y; acc[0][2]+=av.x*bv.z; acc[0][3]+=av.x*bv.w;
            acc[1][0]+=av.y*bv.x; acc[1][1]+=av.y*bv.y; acc[1][2]+=av.y*bv.z; acc[1][3]+=av.y*bv.w;
            acc[2][0]+=av.z*bv.x; acc[2][1]+=av.z*bv.y; acc[2][2]+=av.z*bv.z; acc[2][3]+=av.z*bv.w;
            acc[3][0]+=av.w*bv.x; acc[3][1]+=av.w*bv.y; acc[3][2]+=av.w*bv.z; acc[3][3]+=av.w*bv.w;
        }
    }
    #pragma unroll
    for (int i=0;i<4;++i){
        int gm = m0g + 4*mt + i;
        #pragma unroll
        for (int j=0;j<4;++j){
            int gn = n0g + 4*nt + j;
            float v = acc[i][j];
            if (bias) v += bias[gn];
            C[(size_t)gm*ldc + gn] = v;
        }
    }
}

// =====================================================================
// bf16 MFMA GEMM: block tile 32(M) x 128(N), KT=32, 256 thr (4 waves)
// wave w: rows [(w>>1)*16, +16), cols [(w&1)*64, +64) = 4 mfma tiles
// A fp32 in global (converted to bf16 on load); B bf16 (N,K) layout.
// =====================================================================
#define ASTR 40   // LDS row stride (bf16 elems): 32 + 8 pad
__device__ void gemm_mfma(const float* __restrict__ A1, int lda1, int ksplit,
                          const float* __restrict__ A2, int lda2,
                          const unsigned short* __restrict__ B, int ldb,
                          const float* __restrict__ bias,
                          float* __restrict__ C, int ldc,
                          int K, int k0, int mtile, int ntile)
{
    __shared__ __align__(16) unsigned short As[32*ASTR];
    __shared__ __align__(16) unsigned short Bs[128*ASTR];
    const int tid = threadIdx.x;
    const int lane = tid & 63, w = tid >> 6;
    const int wm = (w >> 1) * 16, wn = (w & 1) * 64;
    const int fr = lane & 15, koff = (lane >> 4) * 8;
    const int m0g = mtile*32, n0g = ntile*128;

    f32x4 acc[4];
    #pragma unroll
    for (int j=0;j<4;++j) acc[j] = (f32x4){0.f,0.f,0.f,0.f};

    // loader indices
    const int arow = tid >> 3, akc = (tid & 7) * 4;           // A: 1 x 4-elem chunk
    for (int kt = 0; kt < K; kt += 32) {
        __syncthreads();
        {   // A tile: 32 rows x 32 k, fp32 -> bf16
            int gk = k0 + kt + akc;
            int gm = m0g + arow;
            const float* src = (gk < ksplit) ? (A1 + (size_t)gm*lda1 + gk)
                                             : (A2 + (size_t)gm*lda2 + (gk - ksplit));
            float4 v = *(const float4*)src;
            unsigned short* d = &As[arow*ASTR + akc];
            d[0] = f2bf(v.x); d[1] = f2bf(v.y); d[2] = f2bf(v.z); d[3] = f2bf(v.w);
        }
        #pragma unroll
        for (int i=0;i<4;++i){   // B tile: 128 rows x 32 k, bf16 direct
            int e = tid + i*256;
            int n = e >> 3, kc = (e & 7) * 4;
            ushort4 bv = *(const ushort4*)(B + (size_t)(n0g + n)*ldb + (k0 + kt + kc));
            unsigned short* d = &Bs[n*ASTR + kc];
            d[0] = bv.x; d[1] = bv.y; d[2] = bv.z; d[3] = bv.w;
        }
        __syncthreads();
        s16x8 af = *(const s16x8*)&As[(wm + fr)*ASTR + koff];
        #pragma unroll
        for (int j=0;j<4;++j){
            s16x8 bf = *(const s16x8*)&Bs[(wn + j*16 + fr)*ASTR + koff];
            acc[j] = __builtin_amdgcn_mfma_f32_16x16x32_bf16(af, bf, acc[j], 0, 0, 0);
        }
    }
    #pragma unroll
    for (int j=0;j<4;++j){
        int gn = n0g + wn + j*16 + fr;
        float bb = bias ? bias[gn] : 0.f;
        #pragma unroll
        for (int r=0;r<4;++r){
            int gm = m0g + wm + (lane >> 4)*4 + r;
            C[(size_t)gm*ldc + gn] = acc[j][r] + bb;
        }
    }
}

// =====================================================================
// prep kernels
// =====================================================================
__global__ __launch_bounds__(256) void k_prep_convert(
    const float* __restrict__ hyp_Wx, const float* __restrict__ hyp_Wh,
    const float* __restrict__ hyp_bx, const float* __restrict__ hyp_bh,
    const float* __restrict__ Wx, const float* __restrict__ Wh,
    unsigned short* __restrict__ wcat1bf, unsigned short* __restrict__ wxbf,
    unsigned short* __restrict__ whbf, float* __restrict__ bias1,
    float* __restrict__ act1, float* __restrict__ c, float* __restrict__ ch)
{
    size_t i = (size_t)blockIdx.x*256 + threadIdx.x;
    if (i < 1572864u) {   // Wcat1 = [hyp_Wx | hyp_Wh], (1024,1536)
        int n = (int)(i / 1536), k = (int)(i % 1536);
        float v = (k < 1280) ? hyp_Wx[(size_t)n*1280 + k] : hyp_Wh[(size_t)n*256 + (k-1280)];
        wcat1bf[i] = f2bf(v); return;
    }
    i -= 1572864u;
    if (i < 1048576u) { wxbf[i] = f2bf(Wx[i]); return; }
    i -= 1048576u;
    if (i < 4194304u) { whbf[i] = f2bf(Wh[i]); return; }
    i -= 4194304u;
    if (i < 1024u) { bias1[i] = hyp_bx[i] + hyp_bh[i]; return; }
    i -= 1024u;
    if (i < 163840u) { act1[i] = 0.f; return; }
    i -= 163840u;
    if (i < 131072u) { c[i] = 0.f; return; }
    i -= 131072u;
    if (i < 32768u) { ch[i] = 0.f; return; }
}

// Wcomb f32: (k<8 ? zw_w[k]@alpha[k] : zb[k-8]@zbeta[k-8])  (256 x 1024)
__global__ __launch_bounds__(128) void k_prep_wcomb(
    const float* __restrict__ zw_w, const float* __restrict__ zb,
    const float* __restrict__ alpha, const float* __restrict__ zbeta,
    float* __restrict__ wcombf32)
{
    int kk = blockIdx.z;
    const float* A = (kk < 8) ? (zw_w + (size_t)kk*65536) : (zb + (size_t)(kk-8)*65536);
    const float* Bm = (kk < 8) ? (alpha + (size_t)kk*262144) : (zbeta + (size_t)(kk-8)*262144);
    gemm_dev(A, 256, KSPLIT_NONE, A, 256, Bm, 1024, 0, nullptr,
             wcombf32 + (size_t)kk*262144, 1024, 256, 0, blockIdx.x, blockIdx.y);
}

// transpose+convert: wcombbf[kk][n][k] = bf16(wcombf32[kk][k][n])
__global__ __launch_bounds__(256) void k_prep_cvtcomb(
    const float* __restrict__ wcombf32, unsigned short* __restrict__ wcombbf)
{
    size_t i = (size_t)blockIdx.x*256 + threadIdx.x;
    if (i >= 3145728u) return;
    int kk = (int)(i / 262144u);
    int r  = (int)(i % 262144u);
    int n = r / 256, k = r % 256;
    wcombbf[i] = f2bf(wcombf32[(size_t)kk*262144 + (size_t)k*1024 + n]);
}

__global__ __launch_bounds__(256) void k_prep_bcomb(
    const float* __restrict__ zw_b, const float* __restrict__ alpha,
    float* __restrict__ bcomb)
{
    int k = blockIdx.x;
    int n = blockIdx.y*256 + threadIdx.x;
    float s = 0.f;
    for (int p=0;p<256;++p)
        s += zw_b[k*256+p] * alpha[(size_t)k*262144 + (size_t)p*1024 + n];
    bcomb[(size_t)k*1024 + n] = s;
}

// =====================================================================
// pointwise cell bodies (shared by standalone kernels and persistent)
// =====================================================================
__device__ __forceinline__ void breduce2(float& a, float& b, volatile float* buf, int tid){
    #pragma unroll
    for (int off = 32; off > 0; off >>= 1) { a += __shfl_xor(a, off); b += __shfl_xor(b, off); }
    __syncthreads();
    if ((tid & 63) == 0) { buf[(tid>>6)*2] = a; buf[(tid>>6)*2+1] = b; }
    __syncthreads();
    a = buf[0] + buf[2] + buf[4] + buf[6];
    b = buf[1] + buf[3] + buf[5] + buf[7];
}

__device__ __forceinline__ void hyper_cell_body(
    const float* __restrict__ lna_g, const float* __restrict__ lna_b,
    const float* __restrict__ ln_g, const float* __restrict__ ln_b,
    const float* __restrict__ gpart, const float* __restrict__ bias1,
    float* __restrict__ ch, float* __restrict__ act1, int b, int tid)
{
    __shared__ float buf[8];
    float v[4];
    #pragma unroll
    for (int g=0; g<4; ++g){
        int idx = b*1024 + g*256 + tid;
        v[g] = gpart[idx] + gpart[131072 + idx] + gpart[262144 + idx] + gpart[393216 + idx]
             + bias1[g*256 + tid];
    }
    #pragma unroll
    for (int g=0; g<4; ++g){
        float s = v[g], ss = v[g]*v[g];
        breduce2(s, ss, buf, tid);
        float m = s * (1.f/256.f);
        float var = ss * (1.f/256.f) - m*m;
        v[g] = (v[g]-m)*rsqrtf(var + EPS)*lna_g[g*256+tid] + lna_b[g*256+tid];
    }
    float chp = ch[b*256 + tid];
    float cn = sigm(v[1])*chp + sigm(v[0])*tanhf(v[2]);
    float s = cn, ss = cn*cn;
    breduce2(s, ss, buf, tid);
    float m = s*(1.f/256.f);
    float var = ss*(1.f/256.f) - m*m;
    float hn = sigm(v[3]) * tanhf((cn-m)*rsqrtf(var + EPS)*ln_g[tid] + ln_b[tid]);
    ch[b*256 + tid] = cn;
    act1[b*1280 + 1024 + tid] = hn;
}

__device__ __forceinline__ void main_cell_body(
    const float* __restrict__ bias4,
    const float* __restrict__ lna_g, const float* __restrict__ lna_b,
    const float* __restrict__ ln_g, const float* __restrict__ ln_b,
    const float* __restrict__ xghg, const float* __restrict__ scb,
    float* __restrict__ c, float* __restrict__ act1, int b, int tid)
{
    __shared__ float buf[8];
    float gn[4][4];
    #pragma unroll
    for (int k=0;k<4;++k){
        float pre[4]; float s=0.f, ss=0.f;
        #pragma unroll
        for (int j=0;j<4;++j){
            int h = j*256 + tid;
            int n = k*1024 + h;
            int bh = b*1024 + h;
            float xgv = xghg[b*4096 + n];
            float hgv = xghg[524288 + b*4096 + n];
            float p = scb[k*131072 + bh]*xgv + scb[(4+k)*131072 + bh]*hgv
                    + bias4[n] + scb[(8+k)*131072 + bh];
            pre[j] = p; s += p; ss += p*p;
        }
        breduce2(s, ss, buf, tid);
        float m = s*(1.f/1024.f);
        float var = ss*(1.f/1024.f) - m*m;
        float rs = rsqrtf(var + EPS);
        #pragma unroll
        for (int j=0;j<4;++j){
            int h=j*256+tid, n=k*1024+h;
            gn[k][j] = (pre[j]-m)*rs*lna_g[n] + lna_b[n];
        }
    }
    float cnv[4]; float s=0.f, ss=0.f;
    #pragma unroll
    for (int j=0;j<4;++j){
        int h=j*256+tid;
        float cv = c[b*1024+h];
        float x = sigm(gn[2][j])*cv + sigm(gn[0][j])*tanhf(gn[1][j]);
        cnv[j]=x; s+=x; ss+=x*x;
    }
    breduce2(s, ss, buf, tid);
    float m=s*(1.f/1024.f);
    float var=ss*(1.f/1024.f)-m*m;
    float rs=rsqrtf(var + EPS);
    #pragma unroll
    for (int j=0;j<4;++j){
        int h=j*256+tid;
        float hv = sigm(gn[3][j])*tanhf((cnv[j]-m)*rs*ln_g[h] + ln_b[h]);
        c[b*1024+h] = cnv[j];
        act1[b*1280 + h] = hv;
    }
}

// =====================================================================
// standalone step kernels (fallback path)
// =====================================================================
__global__ __launch_bounds__(256) void k_step1(
    const float* __restrict__ xt, const float* __restrict__ act1,
    const unsigned short* __restrict__ wcat1bf,
    const unsigned short* __restrict__ wxbf, const unsigned short* __restrict__ whbf,
    float* __restrict__ gpart, float* __restrict__ xghg)
{
    int bid = blockIdx.x;
    if (bid < 128) {          // hyper gates: [xt|h|hh] @ Wcat1^T, split-K 4
        int sp = bid >> 5, r = bid & 31;
        gemm_mfma(xt, 256, 256, act1, 1280, wcat1bf, 1536, nullptr,
                  gpart + (size_t)sp*131072, 1024, 384, sp*384, r >> 3, r & 7);
    } else if (bid < 256) {   // xg = xt @ Wx^T  (128 x 4096, K=256)
        int r = bid - 128;
        gemm_mfma(xt, 256, KSPLIT_NONE, xt, 256, wxbf, 256, nullptr,
                  xghg, 4096, 256, 0, r >> 5, r & 31);
    } else {                  // hg = h @ Wh^T   (128 x 4096, K=1024)
        int r = bid - 256;
        gemm_mfma(act1, 1280, KSPLIT_NONE, act1, 1280, whbf, 1024, nullptr,
                  xghg + 524288, 4096, 1024, 0, r >> 5, r & 31);
    }
}

__global__ __launch_bounds__(256) void k_step2(
    const float* __restrict__ act1, const unsigned short* __restrict__ wcombbf,
    const float* __restrict__ bcomb, float* __restrict__ scb)
{
    int bid = blockIdx.x;
    int kk = bid >> 5, r = bid & 31;
    const float* bias = (kk < 8) ? (bcomb + (size_t)kk*1024) : nullptr;
    gemm_mfma(act1 + 1024, 1280, KSPLIT_NONE, act1 + 1024, 1280,
              wcombbf + (size_t)kk*262144, 256, bias,
              scb + (size_t)kk*131072, 1024, 256, 0, r >> 3, r & 7);
}

__global__ __launch_bounds__(256) void k_hyper_cell(
    const float* __restrict__ lna_g, const float* __restrict__ lna_b,
    const float* __restrict__ ln_g, const float* __restrict__ ln_b,
    const float* __restrict__ gpart, const float* __restrict__ bias1,
    float* __restrict__ ch, float* __restrict__ act1)
{
    hyper_cell_body(lna_g, lna_b, ln_g, ln_b, gpart, bias1, ch, act1,
                    blockIdx.x, threadIdx.x);
}

__global__ __launch_bounds__(256) void k_main_cell(
    const float* __restrict__ bias4,
    const float* __restrict__ lna_g, const float* __restrict__ lna_b,
    const float* __restrict__ ln_g, const float* __restrict__ ln_b,
    const float* __restrict__ xghg, const float* __restrict__ scb,
    float* __restrict__ c, float* __restrict__ act1)
{
    main_cell_body(bias4, lna_g, lna_b, ln_g, ln_b, xghg, scb, c, act1,
                   blockIdx.x, threadIdx.x);
}

// =====================================================================
// persistent cooperative kernel: all 512 steps, 4 grid syncs per step
// grid = 384 blocks x 256 threads (mirrors the per-step grids exactly)
// __launch_bounds__(256,2): >=2 blocks/CU guaranteed -> 512 >= 384 OK
// =====================================================================
__global__ __launch_bounds__(256, 2) void k_persistent(
    const float* __restrict__ x,
    const unsigned short* __restrict__ wcat1bf,
    const unsigned short* __restrict__ wxbf,
    const unsigned short* __restrict__ whbf,
    const unsigned short* __restrict__ wcombbf,
    const float* __restrict__ bcomb,
    const float* __restrict__ bias1,
    const float* __restrict__ bias4,
    const float* __restrict__ lna_g, const float* __restrict__ lna_b,
    const float* __restrict__ ln_g, const float* __restrict__ ln_b,
    const float* __restrict__ hlna_g, const float* __restrict__ hlna_b,
    const float* __restrict__ hln_g, const float* __restrict__ hln_b,
    float* __restrict__ gpart, float* __restrict__ scb,
    float* __restrict__ xghg, float* __restrict__ act1,
    float* __restrict__ c, float* __restrict__ ch)
{
    cg::grid_group grid = cg::this_grid();
    const int bid = blockIdx.x;
    const int tid = threadIdx.x;

    for (int t = 0; t < T_STEPS; ++t) {
        const float* xt = x + (size_t)t*BATCH*DIN;

        // ---- phase A: hyper gates (split-K 4) + xg + hg ----
        if (bid < 128) {
            int sp = bid >> 5, r = bid & 31;
            gemm_mfma(xt, 256, 256, act1, 1280, wcat1bf, 1536, nullptr,
                      gpart + (size_t)sp*131072, 1024, 384, sp*384, r >> 3, r & 7);
        } else if (bid < 256) {
            int r = bid - 128;
            gemm_mfma(xt, 256, KSPLIT_NONE, xt, 256, wxbf, 256, nullptr,
                      xghg, 4096, 256, 0, r >> 5, r & 31);
        } else {
            int r = bid - 256;
            gemm_mfma(act1, 1280, KSPLIT_NONE, act1, 1280, whbf, 1024, nullptr,
                      xghg + 524288, 4096, 1024, 0, r >> 5, r & 31);
        }
        grid.sync();

        // ---- phase B: hyper cell ----
        if (bid < 128)
            hyper_cell_body(hlna_g, hlna_b, hln_g, hln_b, gpart, bias1, ch, act1, bid, tid);
        grid.sync();

        // ---- phase C: 12 x (hyp @ Wcomb[k]) ----
        {
            int kk = bid >> 5, r = bid & 31;
            const float* bias = (kk < 8) ? (bcomb + (size_t)kk*1024) : nullptr;
            gemm_mfma(act1 + 1024, 1280, KSPLIT_NONE, act1 + 1024, 1280,
                      wcombbf + (size_t)kk*262144, 256, bias,
                      scb + (size_t)kk*131072, 1024, 256, 0, r >> 3, r & 7);
        }
        grid.sync();

        // ---- phase D: main cell ----
        if (bid < 128)
            main_cell_body(bias4, lna_g, lna_b, ln_g, ln_b, xghg, scb, c, act1, bid, tid);
        grid.sync();
    }
}

__global__ __launch_bounds__(128) void k_fc(
    const float* __restrict__ fcW, const float* __restrict__ fcb,
    const float* __restrict__ act1, float* __restrict__ out)
{
    int b = blockIdx.x, o = threadIdx.x;
    const float* h = act1 + (size_t)b*1280;
    float s = fcb[o];
    for (int k=0;k<1024;++k) s += h[k]*fcW[(size_t)o*1024 + k];
    out[b*OUTN + o] = s;
}

// =====================================================================
// launch
// =====================================================================
extern "C" void kernel_launch(void* const* d_in, const int* in_sizes, int n_in,
                              void* d_out, int out_size, void* d_ws, size_t ws_size,
                              hipStream_t stream)
{
    const float* x        = (const float*)d_in[0];
    const float* Wx       = (const float*)d_in[1];
    const float* Wh       = (const float*)d_in[2];
    const float* bias     = (const float*)d_in[3];
    const float* lna_g    = (const float*)d_in[4];
    const float* lna_b    = (const float*)d_in[5];
    const float* ln_g     = (const float*)d_in[6];
    const float* ln_b     = (const float*)d_in[7];
    const float* zb       = (const float*)d_in[8];
    const float* zbeta    = (const float*)d_in[9];
    const float* zw_w     = (const float*)d_in[10];
    const float* zw_b     = (const float*)d_in[11];
    const float* alpha    = (const float*)d_in[12];
    const float* hyp_Wx   = (const float*)d_in[13];
    const float* hyp_bx   = (const float*)d_in[14];
    const float* hyp_Wh   = (const float*)d_in[15];
    const float* hyp_bh   = (const float*)d_in[16];
    const float* hlna_g   = (const float*)d_in[17];
    const float* hlna_b   = (const float*)d_in[18];
    const float* hln_g    = (const float*)d_in[19];
    const float* hln_b    = (const float*)d_in[20];
    const float* fcW      = (const float*)d_in[21];
    const float* fcb      = (const float*)d_in[22];
    float* out = (float*)d_out;

    // ---- workspace carve-up (bytes) ----
    unsigned short* wcat1bf = (unsigned short*)d_ws;          // 1024*1536
    unsigned short* wxbf    = wcat1bf + 1572864;              // 4096*256
    unsigned short* whbf    = wxbf + 1048576;                 // 4096*1024
    unsigned short* wcombbf = whbf + 4194304;                 // 12*1024*256
    float* bcomb = (float*)(wcombbf + 3145728);               // 8*1024
    float* bias1 = bcomb + 8192;                              // 1024
    float* act1  = bias1 + 1024;                              // 128*1280 [h|hh] f32
    float* c     = act1 + 163840;                             // 128*1024
    float* ch    = c + 131072;                                // 128*256
    float* stepbuf = ch + 32768;                              // 3,145,728 floats
    float* gpart = stepbuf;                                   // 4*128*1024
    float* scb   = gpart + 524288;                            // 12*128*1024
    float* xghg  = scb + 1572864;                             // 2*128*4096
    float* wcombf32 = stepbuf;                                // prep-time alias

    // ---- prep ----
    k_prep_convert<<<(7144448 + 255)/256, 256, 0, stream>>>(
        hyp_Wx, hyp_Wh, hyp_bx, hyp_bh, Wx, Wh,
        wcat1bf, wxbf, whbf, bias1, act1, c, ch);
    k_prep_wcomb<<<dim3(8,16,12), 128, 0, stream>>>(zw_w, zb, alpha, zbeta, wcombf32);
    k_prep_bcomb<<<dim3(8,4), 256, 0, stream>>>(zw_b, alpha, bcomb);
    k_prep_cvtcomb<<<(3145728 + 255)/256, 256, 0, stream>>>(wcombf32, wcombbf);

    // ---- cooperative-launch capability gate (host-side query, capture-safe) ----
    static int use_coop = -1;
    if (use_coop < 0) {
        use_coop = 0;
        int dev = 0;
        if (hipGetDevice(&dev) == hipSuccess) {
            hipDeviceProp_t prop;
            if (hipGetDeviceProperties(&prop, dev) == hipSuccess &&
                prop.cooperativeLaunch) {
                int occ = 0;
                if (hipOccupancyMaxActiveBlocksPerMultiprocessor(
                        &occ, (const void*)k_persistent, 256, 0) == hipSuccess &&
                    occ * prop.multiProcessorCount >= 384) {
                    use_coop = 1;
                }
            }
        }
    }

    int coop_launched = 0;
    if (use_coop) {
        void* cargs[] = {
            (void*)&x, (void*)&wcat1bf, (void*)&wxbf, (void*)&whbf, (void*)&wcombbf,
            (void*)&bcomb, (void*)&bias1, (void*)&bias,
            (void*)&lna_g, (void*)&lna_b, (void*)&ln_g, (void*)&ln_b,
            (void*)&hlna_g, (void*)&hlna_b, (void*)&hln_g, (void*)&hln_b,
            (void*)&gpart, (void*)&scb, (void*)&xghg, (void*)&act1,
            (void*)&c, (void*)&ch
        };
        hipError_t e = hipLaunchCooperativeKernel((const void*)k_persistent,
                                                  dim3(384), dim3(256),
                                                  cargs, 0u, stream);
        if (e == hipSuccess) {
            coop_launched = 1;
        } else {
            (void)hipGetLastError();   // clear error state
            use_coop = 0;              // never retry
        }
    }

    if (!coop_launched) {
        // ---- fallback: 512 sequential steps, 4 launches each ----
        for (int t = 0; t < T_STEPS; ++t) {
            const float* xt = x + (size_t)t*BATCH*DIN;
            k_step1<<<384, 256, 0, stream>>>(xt, act1, wcat1bf, wxbf, whbf, gpart, xghg);
            k_hyper_cell<<<BATCH, 256, 0, stream>>>(hlna_g, hlna_b, hln_g, hln_b,
                                                    gpart, bias1, ch, act1);
            k_step2<<<384, 256, 0, stream>>>(act1, wcombbf, bcomb, scb);
            k_main_cell<<<BATCH, 256, 0, stream>>>(bias, lna_g, lna_b, ln_g, ln_b,
                                                   xghg, scb, c, act1);
        }
    }

    // ---- final projection ----
    k_fc<<<BATCH, 128, 0, stream>>>(fcW, fcb, act1, out);
}

// Round 2
// 34195.572 us; speedup vs baseline: 1.0025x; 1.0025x over previous
//
#include <hip/hip_runtime.h>
#include <hip/hip_cooperative_groups.h>
#include <math.h>

namespace cg = cooperative_groups;

// ---------------- problem dims ----------------
#define T_STEPS 512
#define BATCH   128
#define DIN     256
#define HMAIN   1024
#define HHYP    256
#define OUTN    128
#define EPS     1e-3f

#define KSPLIT_NONE (1<<30)

typedef __attribute__((ext_vector_type(4))) float f32x4;
typedef __attribute__((ext_vector_type(8))) short s16x8;

__device__ __forceinline__ float sigm(float x){ return 1.f/(1.f + expf(-x)); }

__device__ __forceinline__ unsigned short f2bf(float f){
    union { float f; unsigned u; } x; x.f = f;
    unsigned r = x.u + 0x7FFFu + ((x.u >> 16) & 1u);   // RNE
    return (unsigned short)(r >> 16);
}

// =====================================================================
// fp32 tiled GEMM (prep only): tile 32x64, KT=32, 128 thr, 4x4 micro
// =====================================================================
#define BM 32
#define BN 64
#define KT 32
__device__ void gemm_dev(const float* __restrict__ A1, int lda1, int ksplit,
                         const float* __restrict__ A2, int lda2,
                         const float* __restrict__ Bp, int ldb, int b_nk,
                         const float* __restrict__ bias,
                         float* __restrict__ C, int ldc,
                         int K, int k0, int mtile, int ntile)
{
    __shared__ __align__(16) float As[KT][BM+4];
    __shared__ __align__(16) float Bs[KT][BN+4];
    const int tid = threadIdx.x;
    const int mt = tid >> 4, nt = tid & 15;
    const int m0g = mtile*BM, n0g = ntile*BN;
    float acc[4][4];
    #pragma unroll
    for (int i=0;i<4;++i) { acc[i][0]=0;acc[i][1]=0;acc[i][2]=0;acc[i][3]=0; }
    for (int kt = 0; kt < K; kt += KT) {
        __syncthreads();
        #pragma unroll
        for (int i=0;i<8;++i){
            int e = tid + i*128;
            int m = e >> 5, k = e & 31;
            int gk = k0 + kt + k, gm = m0g + m;
            float v = (gk < ksplit) ? A1[(size_t)gm*lda1 + gk]
                                    : A2[(size_t)gm*lda2 + (gk - ksplit)];
            As[k][m] = v;
        }
        if (b_nk) {
            #pragma unroll
            for (int i=0;i<16;++i){
                int e = tid + i*128;
                int n = e >> 5, k = e & 31;
                Bs[k][n] = Bp[(size_t)(n0g + n)*ldb + (k0 + kt + k)];
            }
        } else {
            #pragma unroll
            for (int i=0;i<16;++i){
                int e = tid + i*128;
                int k = e >> 6, n = e & 63;
                Bs[k][n] = Bp[(size_t)(k0 + kt + k)*ldb + (n0g + n)];
            }
        }
        __syncthreads();
        #pragma unroll
        for (int k=0;k<KT;++k){
            float4 av = *(const float4*)(&As[k][4*mt]);
            float4 bv = *(const float4*)(&Bs[k][4*nt]);
            acc[0][0]+=av.x*bv.x; acc[0][1]+=av.x*bv.y; acc[0][2]+=av.x*bv.z; acc[0][3]+=av.x*bv.w;
            acc[1][0]+=av.y*bv.x; acc[1][1]+=av.y*bv.y; acc[1][2]+=av.y*bv.z; acc[1][3]+=av.y*bv.w;
            acc[2][0]+=av.z*bv.x; acc[2][1]+=av.z*bv.y; acc[2][2]+=av.z*bv.z; acc[2][3]+=av.z*bv.w;
            acc[3][0]+=av.w*bv.x; acc[3][1]+=av.w*bv.y; acc[3][2]+=av.w*bv.z; acc[3][3]+=av.w*bv.w;
        }
    }
    #pragma unroll
    for (int i=0;i<4;++i){
        int gm = m0g + 4*mt + i;
        #pragma unroll
        for (int j=0;j<4;++j){
            int gn = n0g + 4*nt + j;
            float v = acc[i][j];
            if (bias) v += bias[gn];
            C[(size_t)gm*ldc + gn] = v;
        }
    }
}

// =====================================================================
// OLD bf16 MFMA GEMM (fallback path only): tile 32x128, staging in LDS
// =====================================================================
#define ASTR 40
__device__ void gemm_mfma(const float* __restrict__ A1, int lda1, int ksplit,
                          const float* __restrict__ A2, int lda2,
                          const unsigned short* __restrict__ B, int ldb,
                          const float* __restrict__ bias,
                          float* __restrict__ C, int ldc,
                          int K, int k0, int mtile, int ntile)
{
    __shared__ __align__(16) unsigned short As[32*ASTR];
    __shared__ __align__(16) unsigned short Bs[128*ASTR];
    const int tid = threadIdx.x;
    const int lane = tid & 63, w = tid >> 6;
    const int wm = (w >> 1) * 16, wn = (w & 1) * 64;
    const int fr = lane & 15, koff = (lane >> 4) * 8;
    const int m0g = mtile*32, n0g = ntile*128;

    f32x4 acc[4];
    #pragma unroll
    for (int j=0;j<4;++j) acc[j] = (f32x4){0.f,0.f,0.f,0.f};

    const int arow = tid >> 3, akc = (tid & 7) * 4;
    for (int kt = 0; kt < K; kt += 32) {
        __syncthreads();
        {
            int gk = k0 + kt + akc;
            int gm = m0g + arow;
            const float* src = (gk < ksplit) ? (A1 + (size_t)gm*lda1 + gk)
                                             : (A2 + (size_t)gm*lda2 + (gk - ksplit));
            float4 v = *(const float4*)src;
            unsigned short* d = &As[arow*ASTR + akc];
            d[0] = f2bf(v.x); d[1] = f2bf(v.y); d[2] = f2bf(v.z); d[3] = f2bf(v.w);
        }
        #pragma unroll
        for (int i=0;i<4;++i){
            int e = tid + i*256;
            int n = e >> 3, kc = (e & 7) * 4;
            ushort4 bv = *(const ushort4*)(B + (size_t)(n0g + n)*ldb + (k0 + kt + kc));
            unsigned short* d = &Bs[n*ASTR + kc];
            d[0] = bv.x; d[1] = bv.y; d[2] = bv.z; d[3] = bv.w;
        }
        __syncthreads();
        s16x8 af = *(const s16x8*)&As[(wm + fr)*ASTR + koff];
        #pragma unroll
        for (int j=0;j<4;++j){
            s16x8 bf = *(const s16x8*)&Bs[(wn + j*16 + fr)*ASTR + koff];
            acc[j] = __builtin_amdgcn_mfma_f32_16x16x32_bf16(af, bf, acc[j], 0, 0, 0);
        }
    }
    #pragma unroll
    for (int j=0;j<4;++j){
        int gn = n0g + wn + j*16 + fr;
        float bb = bias ? bias[gn] : 0.f;
        #pragma unroll
        for (int r=0;r<4;++r){
            int gm = m0g + wm + (lane >> 4)*4 + r;
            C[(size_t)gm*ldc + gn] = acc[j][r] + bb;
        }
    }
}

// =====================================================================
// NEW weights-in-LDS GEMM: M=128 (full batch), N = NF*16, K=256 fixed.
// Weight tile resident in LDS (stride 264). A read straight to regs.
// No __syncthreads in the loop. 4 waves: wave w owns rows [32w,32w+32).
// =====================================================================
#define WSTR 264
template<int NF, bool AF32>
__device__ __forceinline__ void gemm_ws(
    const void* __restrict__ Aptr, int lda,            // elements
    const unsigned short* wtile,                       // LDS tile [NF*16][WSTR]
    const float* __restrict__ bias,                    // local col bias or null
    float* __restrict__ Cout, int ldc,
    int lane, int w)
{
    const int fr = lane & 15, kq = lane >> 4;
    f32x4 acc[2][NF];
    #pragma unroll
    for (int mf=0; mf<2; ++mf)
        #pragma unroll
        for (int nf=0; nf<NF; ++nf) acc[mf][nf] = (f32x4){0.f,0.f,0.f,0.f};
    const int r0 = w*32 + fr;
    #pragma unroll
    for (int kt=0; kt<256; kt+=32) {
        const int k = kt + kq*8;
        s16x8 a[2];
        #pragma unroll
        for (int mf=0; mf<2; ++mf) {
            const int row = r0 + mf*16;
            if (AF32) {
                const float* s = (const float*)Aptr + (size_t)row*lda + k;
                float4 v0 = *(const float4*)s;
                float4 v1 = *(const float4*)(s+4);
                union { s16x8 v; unsigned short u[8]; } tc;
                tc.u[0]=f2bf(v0.x); tc.u[1]=f2bf(v0.y); tc.u[2]=f2bf(v0.z); tc.u[3]=f2bf(v0.w);
                tc.u[4]=f2bf(v1.x); tc.u[5]=f2bf(v1.y); tc.u[6]=f2bf(v1.z); tc.u[7]=f2bf(v1.w);
                a[mf] = tc.v;
            } else {
                a[mf] = *(const s16x8*)((const unsigned short*)Aptr + (size_t)row*lda + k);
            }
        }
        #pragma unroll
        for (int nf=0; nf<NF; ++nf) {
            s16x8 b = *(const s16x8*)&wtile[(nf*16+fr)*WSTR + k];
            acc[0][nf] = __builtin_amdgcn_mfma_f32_16x16x32_bf16(a[0], b, acc[0][nf], 0,0,0);
            acc[1][nf] = __builtin_amdgcn_mfma_f32_16x16x32_bf16(a[1], b, acc[1][nf], 0,0,0);
        }
    }
    #pragma unroll
    for (int nf=0; nf<NF; ++nf) {
        const int col = nf*16 + fr;
        const float bb = bias ? bias[col] : 0.f;
        #pragma unroll
        for (int mf=0; mf<2; ++mf) {
            const int row = w*32 + mf*16 + kq*4;
            #pragma unroll
            for (int r=0; r<4; ++r)
                Cout[(size_t)(row+r)*ldc + col] = acc[mf][nf][r] + bb;
        }
    }
}

// copy a [rows x 256] bf16 tile (row stride ld) into LDS (stride WSTR)
__device__ __forceinline__ void load_wtile(const unsigned short* __restrict__ src,
                                           int ld, unsigned short* dst, int rows, int tid)
{
    const int chunks = rows * 32;       // 8-elem (16B) chunks
    for (int cidx = tid; cidx < chunks; cidx += 256) {
        const int r = cidx >> 5, k8 = (cidx & 31) << 3;
        *(uint4*)&dst[r*WSTR + k8] = *(const uint4*)&src[(size_t)r*ld + k8];
    }
}

// =====================================================================
// prep kernels
// =====================================================================
__global__ __launch_bounds__(256) void k_prep_convert(
    const float* __restrict__ hyp_Wx, const float* __restrict__ hyp_Wh,
    const float* __restrict__ hyp_bx, const float* __restrict__ hyp_bh,
    const float* __restrict__ Wx, const float* __restrict__ Wh,
    unsigned short* __restrict__ wcat1bf, unsigned short* __restrict__ wxbf,
    unsigned short* __restrict__ whbf, float* __restrict__ bias1,
    float* __restrict__ act1f, float* __restrict__ c, float* __restrict__ ch,
    unsigned int* __restrict__ act1bf_zero)
{
    size_t i = (size_t)blockIdx.x*256 + threadIdx.x;
    if (i < 1572864u) {   // Wcat1 = [hyp_Wx | hyp_Wh], (1024,1536)
        int n = (int)(i / 1536), k = (int)(i % 1536);
        float v = (k < 1280) ? hyp_Wx[(size_t)n*1280 + k] : hyp_Wh[(size_t)n*256 + (k-1280)];
        wcat1bf[i] = f2bf(v); return;
    }
    i -= 1572864u;
    if (i < 1048576u) { wxbf[i] = f2bf(Wx[i]); return; }
    i -= 1048576u;
    if (i < 4194304u) { whbf[i] = f2bf(Wh[i]); return; }
    i -= 4194304u;
    if (i < 1024u) { bias1[i] = hyp_bx[i] + hyp_bh[i]; return; }
    i -= 1024u;
    if (i < 163840u) { act1f[i] = 0.f; return; }
    i -= 163840u;
    if (i < 131072u) { c[i] = 0.f; return; }
    i -= 131072u;
    if (i < 32768u) { ch[i] = 0.f; return; }
    i -= 32768u;
    if (i < 81920u && act1bf_zero) { act1bf_zero[i] = 0u; return; }
}
#define PREP_TOTAL 7225568u

__global__ __launch_bounds__(128) void k_prep_wcomb(
    const float* __restrict__ zw_w, const float* __restrict__ zb,
    const float* __restrict__ alpha, const float* __restrict__ zbeta,
    float* __restrict__ wcombf32)
{
    int kk = blockIdx.z;
    const float* A = (kk < 8) ? (zw_w + (size_t)kk*65536) : (zb + (size_t)(kk-8)*65536);
    const float* Bm = (kk < 8) ? (alpha + (size_t)kk*262144) : (zbeta + (size_t)(kk-8)*262144);
    gemm_dev(A, 256, KSPLIT_NONE, A, 256, Bm, 1024, 0, nullptr,
             wcombf32 + (size_t)kk*262144, 1024, 256, 0, blockIdx.x, blockIdx.y);
}

__global__ __launch_bounds__(256) void k_prep_cvtcomb(
    const float* __restrict__ wcombf32, unsigned short* __restrict__ wcombbf)
{
    size_t i = (size_t)blockIdx.x*256 + threadIdx.x;
    if (i >= 3145728u) return;
    int kk = (int)(i / 262144u);
    int r  = (int)(i % 262144u);
    int n = r / 256, k = r % 256;
    wcombbf[i] = f2bf(wcombf32[(size_t)kk*262144 + (size_t)k*1024 + n]);
}

__global__ __launch_bounds__(256) void k_prep_bcomb(
    const float* __restrict__ zw_b, const float* __restrict__ alpha,
    float* __restrict__ bcomb)
{
    int k = blockIdx.x;
    int n = blockIdx.y*256 + threadIdx.x;
    float s = 0.f;
    for (int p=0;p<256;++p)
        s += zw_b[k*256+p] * alpha[(size_t)k*262144 + (size_t)p*1024 + n];
    bcomb[(size_t)k*1024 + n] = s;
}

// =====================================================================
// reductions / cell bodies
// =====================================================================
__device__ __forceinline__ void breduce2(float& a, float& b, volatile float* buf, int tid){
    #pragma unroll
    for (int off = 32; off > 0; off >>= 1) { a += __shfl_xor(a, off); b += __shfl_xor(b, off); }
    __syncthreads();
    if ((tid & 63) == 0) { buf[(tid>>6)*2] = a; buf[(tid>>6)*2+1] = b; }
    __syncthreads();
    a = buf[0] + buf[2] + buf[4] + buf[6];
    b = buf[1] + buf[3] + buf[5] + buf[7];
}

// ---- new cells (coop path; bf16 activations, 6/4-way partials) ----
__device__ __forceinline__ void hyper_cell6(
    int b, int tid, volatile float* cbuf,
    const float* __restrict__ gpart, const float* __restrict__ bias1,
    const float* __restrict__ lna_g, const float* __restrict__ lna_b,
    const float* __restrict__ ln_g, const float* __restrict__ ln_b,
    float* __restrict__ ch, unsigned short* __restrict__ act1bf)
{
    float v[4];
    #pragma unroll
    for (int g=0; g<4; ++g){
        size_t idx = (size_t)b*1024 + g*256 + tid;
        v[g] = gpart[idx] + gpart[131072+idx] + gpart[262144+idx]
             + gpart[393216+idx] + gpart[524288+idx] + gpart[655360+idx]
             + bias1[g*256 + tid];
    }
    #pragma unroll
    for (int g=0; g<4; ++g){
        float s = v[g], ss = v[g]*v[g];
        breduce2(s, ss, cbuf, tid);
        float m = s * (1.f/256.f);
        float var = ss * (1.f/256.f) - m*m;
        v[g] = (v[g]-m)*rsqrtf(var + EPS)*lna_g[g*256+tid] + lna_b[g*256+tid];
    }
    float chp = ch[b*256 + tid];
    float cn = sigm(v[1])*chp + sigm(v[0])*tanhf(v[2]);
    float s = cn, ss = cn*cn;
    breduce2(s, ss, cbuf, tid);
    float m = s*(1.f/256.f);
    float var = ss*(1.f/256.f) - m*m;
    float hn = sigm(v[3]) * tanhf((cn-m)*rsqrtf(var + EPS)*ln_g[tid] + ln_b[tid]);
    ch[b*256 + tid] = cn;
    act1bf[(size_t)b*1280 + 1024 + tid] = f2bf(hn);
}

__device__ __forceinline__ void main_cell2(
    int b, int tid, volatile float* cbuf,
    const float* __restrict__ bias4,
    const float* __restrict__ lna_g, const float* __restrict__ lna_b,
    const float* __restrict__ ln_g, const float* __restrict__ ln_b,
    const float* __restrict__ xgbuf, const float* __restrict__ hgpart,
    const float* __restrict__ scb,
    float* __restrict__ c, unsigned short* __restrict__ act1bf,
    float* __restrict__ hfc)
{
    float gn[4][4];
    #pragma unroll
    for (int k=0;k<4;++k){
        float pre[4]; float s=0.f, ss=0.f;
        #pragma unroll
        for (int j=0;j<4;++j){
            int h = j*256 + tid;
            int n = k*1024 + h;
            size_t bh = (size_t)b*1024 + h;
            size_t bn = (size_t)b*4096 + n;
            float xgv = xgbuf[bn];
            float hgv = hgpart[bn] + hgpart[524288+bn] + hgpart[1048576+bn] + hgpart[1572864+bn];
            float p = scb[(size_t)k*131072 + bh]*xgv + scb[(size_t)(4+k)*131072 + bh]*hgv
                    + bias4[n] + scb[(size_t)(8+k)*131072 + bh];
            pre[j] = p; s += p; ss += p*p;
        }
        breduce2(s, ss, cbuf, tid);
        float m = s*(1.f/1024.f);
        float var = ss*(1.f/1024.f) - m*m;
        float rs = rsqrtf(var + EPS);
        #pragma unroll
        for (int j=0;j<4;++j){
            int h=j*256+tid, n=k*1024+h;
            gn[k][j] = (pre[j]-m)*rs*lna_g[n] + lna_b[n];
        }
    }
    float cnv[4]; float s=0.f, ss=0.f;
    #pragma unroll
    for (int j=0;j<4;++j){
        int h=j*256+tid;
        float cv = c[(size_t)b*1024+h];
        float x = sigm(gn[2][j])*cv + sigm(gn[0][j])*tanhf(gn[1][j]);
        cnv[j]=x; s+=x; ss+=x*x;
    }
    breduce2(s, ss, cbuf, tid);
    float m=s*(1.f/1024.f);
    float var=ss*(1.f/1024.f)-m*m;
    float rs=rsqrtf(var + EPS);
    #pragma unroll
    for (int j=0;j<4;++j){
        int h=j*256+tid;
        float hv = sigm(gn[3][j])*tanhf((cnv[j]-m)*rs*ln_g[h] + ln_b[h]);
        c[(size_t)b*1024+h] = cnv[j];
        act1bf[(size_t)b*1280 + h] = f2bf(hv);
        hfc[(size_t)b*1024 + h] = hv;
    }
}

// ---- old cells (fallback path; f32 activations, 4-way gpart) ----
__device__ __forceinline__ void hyper_cell_body(
    const float* __restrict__ lna_g, const float* __restrict__ lna_b,
    const float* __restrict__ ln_g, const float* __restrict__ ln_b,
    const float* __restrict__ gpart, const float* __restrict__ bias1,
    float* __restrict__ ch, float* __restrict__ act1, int b, int tid)
{
    __shared__ float buf[8];
    float v[4];
    #pragma unroll
    for (int g=0; g<4; ++g){
        int idx = b*1024 + g*256 + tid;
        v[g] = gpart[idx] + gpart[131072 + idx] + gpart[262144 + idx] + gpart[393216 + idx]
             + bias1[g*256 + tid];
    }
    #pragma unroll
    for (int g=0; g<4; ++g){
        float s = v[g], ss = v[g]*v[g];
        breduce2(s, ss, buf, tid);
        float m = s * (1.f/256.f);
        float var = ss * (1.f/256.f) - m*m;
        v[g] = (v[g]-m)*rsqrtf(var + EPS)*lna_g[g*256+tid] + lna_b[g*256+tid];
    }
    float chp = ch[b*256 + tid];
    float cn = sigm(v[1])*chp + sigm(v[0])*tanhf(v[2]);
    float s = cn, ss = cn*cn;
    breduce2(s, ss, buf, tid);
    float m = s*(1.f/256.f);
    float var = ss*(1.f/256.f) - m*m;
    float hn = sigm(v[3]) * tanhf((cn-m)*rsqrtf(var + EPS)*ln_g[tid] + ln_b[tid]);
    ch[b*256 + tid] = cn;
    act1[b*1280 + 1024 + tid] = hn;
}

__device__ __forceinline__ void main_cell_body(
    const float* __restrict__ bias4,
    const float* __restrict__ lna_g, const float* __restrict__ lna_b,
    const float* __restrict__ ln_g, const float* __restrict__ ln_b,
    const float* __restrict__ xghg, const float* __restrict__ scb,
    float* __restrict__ c, float* __restrict__ act1, int b, int tid)
{
    __shared__ float buf[8];
    float gn[4][4];
    #pragma unroll
    for (int k=0;k<4;++k){
        float pre[4]; float s=0.f, ss=0.f;
        #pragma unroll
        for (int j=0;j<4;++j){
            int h = j*256 + tid;
            int n = k*1024 + h;
            int bh = b*1024 + h;
            float xgv = xghg[b*4096 + n];
            float hgv = xghg[524288 + b*4096 + n];
            float p = scb[k*131072 + bh]*xgv + scb[(4+k)*131072 + bh]*hgv
                    + bias4[n] + scb[(8+k)*131072 + bh];
            pre[j] = p; s += p; ss += p*p;
        }
        breduce2(s, ss, buf, tid);
        float m = s*(1.f/1024.f);
        float var = ss*(1.f/1024.f) - m*m;
        float rs = rsqrtf(var + EPS);
        #pragma unroll
        for (int j=0;j<4;++j){
            int h=j*256+tid, n=k*1024+h;
            gn[k][j] = (pre[j]-m)*rs*lna_g[n] + lna_b[n];
        }
    }
    float cnv[4]; float s=0.f, ss=0.f;
    #pragma unroll
    for (int j=0;j<4;++j){
        int h=j*256+tid;
        float cv = c[b*1024+h];
        float x = sigm(gn[2][j])*cv + sigm(gn[0][j])*tanhf(gn[1][j]);
        cnv[j]=x; s+=x; ss+=x*x;
    }
    breduce2(s, ss, buf, tid);
    float m=s*(1.f/1024.f);
    float var=ss*(1.f/1024.f)-m*m;
    float rs=rsqrtf(var + EPS);
    #pragma unroll
    for (int j=0;j<4;++j){
        int h=j*256+tid;
        float hv = sigm(gn[3][j])*tanhf((cnv[j]-m)*rs*ln_g[h] + ln_b[h]);
        c[b*1024+h] = cnv[j];
        act1[b*1280 + h] = hv;
    }
}

// =====================================================================
// fallback step kernels (old structure on new buffers)
// =====================================================================
__global__ __launch_bounds__(256) void k_step1(
    const float* __restrict__ xt, const float* __restrict__ act1,
    const unsigned short* __restrict__ wcat1bf,
    const unsigned short* __restrict__ wxbf, const unsigned short* __restrict__ whbf,
    float* __restrict__ gpart, float* __restrict__ xghg)
{
    int bid = blockIdx.x;
    if (bid < 128) {
        int sp = bid >> 5, r = bid & 31;
        gemm_mfma(xt, 256, 256, act1, 1280, wcat1bf, 1536, nullptr,
                  gpart + (size_t)sp*131072, 1024, 384, sp*384, r >> 3, r & 7);
    } else if (bid < 256) {
        int r = bid - 128;
        gemm_mfma(xt, 256, KSPLIT_NONE, xt, 256, wxbf, 256, nullptr,
                  xghg, 4096, 256, 0, r >> 5, r & 31);
    } else {
        int r = bid - 256;
        gemm_mfma(act1, 1280, KSPLIT_NONE, act1, 1280, whbf, 1024, nullptr,
                  xghg + 524288, 4096, 1024, 0, r >> 5, r & 31);
    }
}

__global__ __launch_bounds__(256) void k_step2(
    const float* __restrict__ act1, const unsigned short* __restrict__ wcombbf,
    const float* __restrict__ bcomb, float* __restrict__ scb)
{
    int bid = blockIdx.x;
    int kk = bid >> 5, r = bid & 31;
    const float* bias = (kk < 8) ? (bcomb + (size_t)kk*1024) : nullptr;
    gemm_mfma(act1 + 1024, 1280, KSPLIT_NONE, act1 + 1024, 1280,
              wcombbf + (size_t)kk*262144, 256, bias,
              scb + (size_t)kk*131072, 1024, 256, 0, r >> 3, r & 7);
}

__global__ __launch_bounds__(256) void k_hyper_cell(
    const float* __restrict__ lna_g, const float* __restrict__ lna_b,
    const float* __restrict__ ln_g, const float* __restrict__ ln_b,
    const float* __restrict__ gpart, const float* __restrict__ bias1,
    float* __restrict__ ch, float* __restrict__ act1)
{
    hyper_cell_body(lna_g, lna_b, ln_g, ln_b, gpart, bias1, ch, act1,
                    blockIdx.x, threadIdx.x);
}

__global__ __launch_bounds__(256) void k_main_cell(
    const float* __restrict__ bias4,
    const float* __restrict__ lna_g, const float* __restrict__ lna_b,
    const float* __restrict__ ln_g, const float* __restrict__ ln_b,
    const float* __restrict__ xghg, const float* __restrict__ scb,
    float* __restrict__ c, float* __restrict__ act1)
{
    main_cell_body(bias4, lna_g, lna_b, ln_g, ln_b, xghg, scb, c, act1,
                   blockIdx.x, threadIdx.x);
}

// =====================================================================
// persistent cooperative kernel v2: weights resident in LDS.
// 512 blocks x 256 threads, 2 blocks/CU. LDS/block = 50.7 KB.
//
// roles:
//   bid   0- 95: G1  (phase A)  tile n=64, K=256 (6 pure splits of Kcat=1536)
//   bid  96-351: HG  (phase B)  tile n=64, split-K4 over K=1024
//   bid 352-415: XG  (phase B)  tile n=64, K=256
//   bid   0-383: MOD (phase C)  tile n=32, K=256 (12 gemms x 32 ntiles)
//   cell1 (B): bid 416-511 -> rows 0-95, bid 0-31 -> rows 96-127
//   cell2 (D): bid 0-127
// =====================================================================
__global__ __launch_bounds__(256, 2) void k_persist2(
    const float* __restrict__ x,
    const unsigned short* __restrict__ wcat1bf,
    const unsigned short* __restrict__ wxbf,
    const unsigned short* __restrict__ whbf,
    const unsigned short* __restrict__ wcombbf,
    const float* __restrict__ bcomb, const float* __restrict__ bias1,
    const float* __restrict__ bias4,
    const float* __restrict__ lna_g, const float* __restrict__ lna_b,
    const float* __restrict__ ln_g, const float* __restrict__ ln_b,
    const float* __restrict__ hlna_g, const float* __restrict__ hlna_b,
    const float* __restrict__ hln_g, const float* __restrict__ hln_b,
    float* __restrict__ gpart, float* __restrict__ hgpart,
    float* __restrict__ xgbuf, float* __restrict__ scb,
    unsigned short* __restrict__ act1bf, float* __restrict__ hfc,
    float* __restrict__ c, float* __restrict__ ch)
{
    cg::grid_group grid = cg::this_grid();
    const int bid = blockIdx.x, tid = threadIdx.x;
    const int lane = tid & 63, w = tid >> 6;
    __shared__ __align__(16) unsigned short wlds[25344];  // [64][264] + [32][264]
    __shared__ float cbuf[8];

    // ---- one-time weight preload into LDS ----
    if (bid < 96) {
        load_wtile(wcat1bf + (size_t)((bid & 15)*64)*1536 + (bid >> 4)*256,
                   1536, wlds, 64, tid);
    } else if (bid < 352) {
        int h_ = bid - 96;
        load_wtile(whbf + (size_t)((h_ >> 2)*64)*1024 + (h_ & 3)*256,
                   1024, wlds, 64, tid);
    } else if (bid < 416) {
        load_wtile(wxbf + (size_t)(bid - 352)*64*256, 256, wlds, 64, tid);
    }
    if (bid < 384) {
        int kk = bid >> 5, mt = bid & 31;
        load_wtile(wcombbf + (size_t)kk*262144 + (size_t)(mt*32)*256,
                   256, wlds + 16896, 32, tid);
    }
    __syncthreads();

    for (int t = 0; t < T_STEPS; ++t) {
        const float* xt = x + (size_t)t*BATCH*DIN;

        // ---- phase A: hyper gates g1 (6 pure K-splits) ----
        if (bid < 96) {
            int nt = bid & 15, sp = bid >> 4;
            float* outp = gpart + (size_t)sp*131072 + nt*64;
            if (sp == 0)
                gemm_ws<4,true >(xt, 256, wlds, nullptr, outp, 1024, lane, w);
            else
                gemm_ws<4,false>(act1bf + (sp-1)*256, 1280, wlds, nullptr, outp, 1024, lane, w);
        }
        grid.sync();

        // ---- phase B: hg (split-K4) + xg + hyper cell ----
        if (bid >= 96 && bid < 352) {
            int h_ = bid - 96, nt = h_ >> 2, sp = h_ & 3;
            gemm_ws<4,false>(act1bf + sp*256, 1280, wlds, nullptr,
                             hgpart + (size_t)sp*524288 + nt*64, 4096, lane, w);
        } else if (bid >= 352 && bid < 416) {
            gemm_ws<4,true >(xt, 256, wlds, nullptr,
                             xgbuf + (bid - 352)*64, 4096, lane, w);
        } else {
            int row = (bid >= 416) ? (bid - 416) : (bid < 32 ? 96 + bid : -1);
            if (row >= 0)
                hyper_cell6(row, tid, cbuf, gpart, bias1,
                            hlna_g, hlna_b, hln_g, hln_b, ch, act1bf);
        }
        grid.sync();

        // ---- phase C: 12 x (hyp @ Wcomb[k]) ----
        if (bid < 384) {
            int kk = bid >> 5, mt = bid & 31;
            const float* bp = (kk < 8) ? (bcomb + (size_t)kk*1024 + mt*32) : nullptr;
            gemm_ws<2,false>(act1bf + 1024, 1280, wlds + 16896, bp,
                             scb + (size_t)kk*131072 + mt*32, 1024, lane, w);
        }
        grid.sync();

        // ---- phase D: main cell ----
        if (bid < 128)
            main_cell2(bid, tid, cbuf, bias4, lna_g, lna_b, ln_g, ln_b,
                       xgbuf, hgpart, scb, c, act1bf, hfc);
        grid.sync();
    }
}

__global__ __launch_bounds__(128) void k_fc2(
    const float* __restrict__ fcW, const float* __restrict__ fcb,
    const float* __restrict__ hsrc, int ldh, float* __restrict__ out)
{
    int b = blockIdx.x, o = threadIdx.x;
    const float* h = hsrc + (size_t)b*ldh;
    float s = fcb[o];
    for (int k=0;k<1024;++k) s += h[k]*fcW[(size_t)o*1024 + k];
    out[b*OUTN + o] = s;
}

// =====================================================================
// launch
// =====================================================================
extern "C" void kernel_launch(void* const* d_in, const int* in_sizes, int n_in,
                              void* d_out, int out_size, void* d_ws, size_t ws_size,
                              hipStream_t stream)
{
    const float* x        = (const float*)d_in[0];
    const float* Wx       = (const float*)d_in[1];
    const float* Wh       = (const float*)d_in[2];
    const float* bias     = (const float*)d_in[3];
    const float* lna_g    = (const float*)d_in[4];
    const float* lna_b    = (const float*)d_in[5];
    const float* ln_g     = (const float*)d_in[6];
    const float* ln_b     = (const float*)d_in[7];
    const float* zb       = (const float*)d_in[8];
    const float* zbeta    = (const float*)d_in[9];
    const float* zw_w     = (const float*)d_in[10];
    const float* zw_b     = (const float*)d_in[11];
    const float* alpha    = (const float*)d_in[12];
    const float* hyp_Wx   = (const float*)d_in[13];
    const float* hyp_bx   = (const float*)d_in[14];
    const float* hyp_Wh   = (const float*)d_in[15];
    const float* hyp_bh   = (const float*)d_in[16];
    const float* hlna_g   = (const float*)d_in[17];
    const float* hlna_b   = (const float*)d_in[18];
    const float* hln_g    = (const float*)d_in[19];
    const float* hln_b    = (const float*)d_in[20];
    const float* fcW      = (const float*)d_in[21];
    const float* fcb      = (const float*)d_in[22];
    float* out = (float*)d_out;

    // ---- workspace carve (elements) ----
    unsigned short* wcat1bf = (unsigned short*)d_ws;          // 1572864
    unsigned short* wxbf    = wcat1bf + 1572864;              // 1048576
    unsigned short* whbf    = wxbf + 1048576;                 // 4194304
    unsigned short* wcombbf = whbf + 4194304;                 // 3145728
    unsigned short* act1bf  = wcombbf + 3145728;              // 163840 (bf16 [h|hh])
    float* fbase = (float*)(act1bf + 163840);
    float* bcomb = fbase;                                     // 8192
    float* bias1 = bcomb + 8192;                              // 1024
    float* hfc   = bias1 + 1024;                              // 131072 (f32 h for fc)
    float* c     = hfc + 131072;                              // 131072
    float* ch    = c + 131072;                                // 32768
    float* act1o = ch + 32768;                                // 163840 (f32 [h|hh], fallback)
    float* gpart = act1o + 163840;                            // 786432 (6 x 131072)
    float* hgpart= gpart + 786432;                            // 2097152 (4 x 524288)
    float* xgbuf = hgpart + 2097152;                          // 524288
    float* scb   = xgbuf + 524288;                            // 1572864 (12 x 131072)
    float* wcombf32 = gpart;                                  // prep-time alias (3.4M >= 3.1M)

    // ---- prep ----
    k_prep_convert<<<(PREP_TOTAL + 255)/256, 256, 0, stream>>>(
        hyp_Wx, hyp_Wh, hyp_bx, hyp_bh, Wx, Wh,
        wcat1bf, wxbf, whbf, bias1, act1o, c, ch, (unsigned int*)act1bf);
    k_prep_wcomb<<<dim3(8,16,12), 128, 0, stream>>>(zw_w, zb, alpha, zbeta, wcombf32);
    k_prep_bcomb<<<dim3(8,4), 256, 0, stream>>>(zw_b, alpha, bcomb);
    k_prep_cvtcomb<<<(3145728 + 255)/256, 256, 0, stream>>>(wcombf32, wcombbf);

    // ---- cooperative capability gate (host-side, capture-safe) ----
    static int use_coop = -1;
    if (use_coop < 0) {
        use_coop = 0;
        int dev = 0;
        if (hipGetDevice(&dev) == hipSuccess) {
            hipDeviceProp_t prop;
            if (hipGetDeviceProperties(&prop, dev) == hipSuccess &&
                prop.cooperativeLaunch) {
                int occ = 0;
                if (hipOccupancyMaxActiveBlocksPerMultiprocessor(
                        &occ, (const void*)k_persist2, 256, 0) == hipSuccess &&
                    occ >= 2 && occ * prop.multiProcessorCount >= 512) {
                    use_coop = 1;
                }
            }
        }
    }

    int coop_launched = 0;
    if (use_coop) {
        void* cargs[] = {
            (void*)&x, (void*)&wcat1bf, (void*)&wxbf, (void*)&whbf, (void*)&wcombbf,
            (void*)&bcomb, (void*)&bias1, (void*)&bias,
            (void*)&lna_g, (void*)&lna_b, (void*)&ln_g, (void*)&ln_b,
            (void*)&hlna_g, (void*)&hlna_b, (void*)&hln_g, (void*)&hln_b,
            (void*)&gpart, (void*)&hgpart, (void*)&xgbuf, (void*)&scb,
            (void*)&act1bf, (void*)&hfc, (void*)&c, (void*)&ch
        };
        hipError_t e = hipLaunchCooperativeKernel((const void*)k_persist2,
                                                  dim3(512), dim3(256),
                                                  cargs, 0u, stream);
        if (e == hipSuccess) {
            coop_launched = 1;
        } else {
            (void)hipGetLastError();
            use_coop = 0;
        }
    }

    if (!coop_launched) {
        // fallback: old 4-launch structure on the new carve
        float* xghg = hgpart;   // [xg | hg] fits in hgpart region
        for (int t = 0; t < T_STEPS; ++t) {
            const float* xt = x + (size_t)t*BATCH*DIN;
            k_step1<<<384, 256, 0, stream>>>(xt, act1o, wcat1bf, wxbf, whbf, gpart, xghg);
            k_hyper_cell<<<BATCH, 256, 0, stream>>>(hlna_g, hlna_b, hln_g, hln_b,
                                                    gpart, bias1, ch, act1o);
            k_step2<<<384, 256, 0, stream>>>(act1o, wcombbf, bcomb, scb);
            k_main_cell<<<BATCH, 256, 0, stream>>>(bias, lna_g, lna_b, ln_g, ln_b,
                                                   xghg, scb, c, act1o);
        }
        k_fc2<<<BATCH, 128, 0, stream>>>(fcW, fcb, act1o, 1280, out);
        return;
    }

    // ---- final projection (coop path: f32 h copy) ----
    k_fc2<<<BATCH, 128, 0, stream>>>(fcW, fcb, hfc, 1024, out);
}

// Round 3
// 34183.661 us; speedup vs baseline: 1.0028x; 1.0003x over previous
//
#include <hip/hip_runtime.h>
#include <math.h>

// ---------------- problem dims ----------------
#define T_STEPS 512
#define BATCH   128
#define DIN     256
#define HMAIN   1024
#define HHYP    256
#define OUTN    128
#define EPS     1e-3f

#define KSPLIT_NONE (1<<30)
#define NBLK 512

typedef __attribute__((ext_vector_type(4))) float f32x4;
typedef __attribute__((ext_vector_type(8))) short s16x8;

__device__ __forceinline__ float sigm(float x){ return 1.f/(1.f + expf(-x)); }

__device__ __forceinline__ unsigned short f2bf(float f){
    union { float f; unsigned u; } x; x.f = f;
    unsigned r = x.u + 0x7FFFu + ((x.u >> 16) & 1u);   // RNE
    return (unsigned short)(r >> 16);
}

// ---- agent-scope (device-coherent, LLC-routed) access helpers ----
__device__ __forceinline__ float agf(const float* p){
    return __hip_atomic_load(const_cast<float*>(p), __ATOMIC_RELAXED, __HIP_MEMORY_SCOPE_AGENT);
}
__device__ __forceinline__ unsigned long long agu8(const void* p){
    return __hip_atomic_load(const_cast<unsigned long long*>((const unsigned long long*)p),
                             __ATOMIC_RELAXED, __HIP_MEMORY_SCOPE_AGENT);
}
__device__ __forceinline__ void agsf(float* p, float v){
    __hip_atomic_store(p, v, __ATOMIC_RELAXED, __HIP_MEMORY_SCOPE_AGENT);
}
__device__ __forceinline__ void agsu(unsigned* p, unsigned v){
    __hip_atomic_store(p, v, __ATOMIC_RELAXED, __HIP_MEMORY_SCOPE_AGENT);
}

// =====================================================================
// custom grid barrier: NO L2 flush. All cross-phase data is agent-scope
// write-through, so visibility only needs vmcnt(0) (from __syncthreads)
// before the arrive-add. 16 counter lines (128B apart) cut contention.
// =====================================================================
__device__ __forceinline__ void gbar(unsigned* cnt, unsigned phase, int bid, int tid){
    __syncthreads();                       // all threads' sc1 stores drained
    if (tid < 16){
        if (tid == (bid & 15))
            __hip_atomic_fetch_add(&cnt[tid*32], 1u, __ATOMIC_RELAXED, __HIP_MEMORY_SCOPE_AGENT);
        const unsigned tg = phase * (NBLK/16);
        while (__hip_atomic_load(&cnt[tid*32], __ATOMIC_RELAXED, __HIP_MEMORY_SCOPE_AGENT) < tg)
            __builtin_amdgcn_s_sleep(4);
    }
    __syncthreads();
}

// =====================================================================
// fp32 tiled GEMM (prep only): tile 32x64, KT=32, 128 thr, 4x4 micro
// =====================================================================
#define BM 32
#define BN 64
#define KT 32
__device__ void gemm_dev(const float* __restrict__ A1, int lda1, int ksplit,
                         const float* __restrict__ A2, int lda2,
                         const float* __restrict__ Bp, int ldb, int b_nk,
                         const float* __restrict__ bias,
                         float* __restrict__ C, int ldc,
                         int K, int k0, int mtile, int ntile)
{
    __shared__ __align__(16) float As[KT][BM+4];
    __shared__ __align__(16) float Bs[KT][BN+4];
    const int tid = threadIdx.x;
    const int mt = tid >> 4, nt = tid & 15;
    const int m0g = mtile*BM, n0g = ntile*BN;
    float acc[4][4];
    #pragma unroll
    for (int i=0;i<4;++i) { acc[i][0]=0;acc[i][1]=0;acc[i][2]=0;acc[i][3]=0; }
    for (int kt = 0; kt < K; kt += KT) {
        __syncthreads();
        #pragma unroll
        for (int i=0;i<8;++i){
            int e = tid + i*128;
            int m = e >> 5, k = e & 31;
            int gk = k0 + kt + k, gm = m0g + m;
            float v = (gk < ksplit) ? A1[(size_t)gm*lda1 + gk]
                                    : A2[(size_t)gm*lda2 + (gk - ksplit)];
            As[k][m] = v;
        }
        if (b_nk) {
            #pragma unroll
            for (int i=0;i<16;++i){
                int e = tid + i*128;
                int n = e >> 5, k = e & 31;
                Bs[k][n] = Bp[(size_t)(n0g + n)*ldb + (k0 + kt + k)];
            }
        } else {
            #pragma unroll
            for (int i=0;i<16;++i){
                int e = tid + i*128;
                int k = e >> 6, n = e & 63;
                Bs[k][n] = Bp[(size_t)(k0 + kt + k)*ldb + (n0g + n)];
            }
        }
        __syncthreads();
        #pragma unroll
        for (int k=0;k<KT;++k){
            float4 av = *(const float4*)(&As[k][4*mt]);
            float4 bv = *(const float4*)(&Bs[k][4*nt]);
            acc[0][0]+=av.x*bv.x; acc[0][1]+=av.x*bv.y; acc[0][2]+=av.x*bv.z; acc[0][3]+=av.x*bv.w;
            acc[1][0]+=av.y*bv.x; acc[1][1]+=av.y*bv.y; acc[1][2]+=av.y*bv.z; acc[1][3]+=av.y*bv.w;
            acc[2][0]+=av.z*bv.x; acc[2][1]+=av.z*bv.y; acc[2][2]+=av.z*bv.z; acc[2][3]+=av.z*bv.w;
            acc[3][0]+=av.w*bv.x; acc[3][1]+=av.w*bv.y; acc[3][2]+=av.w*bv.z; acc[3][3]+=av.w*bv.w;
        }
    }
    #pragma unroll
    for (int i=0;i<4;++i){
        int gm = m0g + 4*mt + i;
        #pragma unroll
        for (int j=0;j<4;++j){
            int gn = n0g + 4*nt + j;
            float v = acc[i][j];
            if (bias) v += bias[gn];
            C[(size_t)gm*ldc + gn] = v;
        }
    }
}

// =====================================================================
// OLD bf16 MFMA GEMM (fallback path only)
// =====================================================================
#define ASTR 40
__device__ void gemm_mfma(const float* __restrict__ A1, int lda1, int ksplit,
                          const float* __restrict__ A2, int lda2,
                          const unsigned short* __restrict__ B, int ldb,
                          const float* __restrict__ bias,
                          float* __restrict__ C, int ldc,
                          int K, int k0, int mtile, int ntile)
{
    __shared__ __align__(16) unsigned short As[32*ASTR];
    __shared__ __align__(16) unsigned short Bs[128*ASTR];
    const int tid = threadIdx.x;
    const int lane = tid & 63, w = tid >> 6;
    const int wm = (w >> 1) * 16, wn = (w & 1) * 64;
    const int fr = lane & 15, koff = (lane >> 4) * 8;
    const int m0g = mtile*32, n0g = ntile*128;

    f32x4 acc[4];
    #pragma unroll
    for (int j=0;j<4;++j) acc[j] = (f32x4){0.f,0.f,0.f,0.f};

    const int arow = tid >> 3, akc = (tid & 7) * 4;
    for (int kt = 0; kt < K; kt += 32) {
        __syncthreads();
        {
            int gk = k0 + kt + akc;
            int gm = m0g + arow;
            const float* src = (gk < ksplit) ? (A1 + (size_t)gm*lda1 + gk)
                                             : (A2 + (size_t)gm*lda2 + (gk - ksplit));
            float4 v = *(const float4*)src;
            unsigned short* d = &As[arow*ASTR + akc];
            d[0] = f2bf(v.x); d[1] = f2bf(v.y); d[2] = f2bf(v.z); d[3] = f2bf(v.w);
        }
        #pragma unroll
        for (int i=0;i<4;++i){
            int e = tid + i*256;
            int n = e >> 3, kc = (e & 7) * 4;
            ushort4 bv = *(const ushort4*)(B + (size_t)(n0g + n)*ldb + (k0 + kt + kc));
            unsigned short* d = &Bs[n*ASTR + kc];
            d[0] = bv.x; d[1] = bv.y; d[2] = bv.z; d[3] = bv.w;
        }
        __syncthreads();
        s16x8 af = *(const s16x8*)&As[(wm + fr)*ASTR + koff];
        #pragma unroll
        for (int j=0;j<4;++j){
            s16x8 bf = *(const s16x8*)&Bs[(wn + j*16 + fr)*ASTR + koff];
            acc[j] = __builtin_amdgcn_mfma_f32_16x16x32_bf16(af, bf, acc[j], 0, 0, 0);
        }
    }
    #pragma unroll
    for (int j=0;j<4;++j){
        int gn = n0g + wn + j*16 + fr;
        float bb = bias ? bias[gn] : 0.f;
        #pragma unroll
        for (int r=0;r<4;++r){
            int gm = m0g + wm + (lane >> 4)*4 + r;
            C[(size_t)gm*ldc + gn] = acc[j][r] + bb;
        }
    }
}

// =====================================================================
// weights-in-LDS GEMM: M=128 (full batch), N = NF*16, K=256 fixed.
// AMODE 0: A is plain f32 (read-only input xt), converted to bf16.
// AMODE 2: A is bf16, agent-coherent (activations).
// C stores are agent-coherent. No __syncthreads inside.
// =====================================================================
#define WSTR 264
template<int NF, int AMODE>
__device__ __forceinline__ void gemm_ws(
    const void* __restrict__ Aptr, int lda,            // elements of src type
    const unsigned short* wtile,                       // LDS tile [NF*16][WSTR]
    const float* __restrict__ bias,                    // local col bias or null
    float* __restrict__ Cout, int ldc,
    int lane, int w)
{
    const int fr = lane & 15, kq = lane >> 4;
    f32x4 acc[2][NF];
    #pragma unroll
    for (int mf=0; mf<2; ++mf)
        #pragma unroll
        for (int nf=0; nf<NF; ++nf) acc[mf][nf] = (f32x4){0.f,0.f,0.f,0.f};
    const int r0 = w*32 + fr;
    #pragma unroll
    for (int kt=0; kt<256; kt+=32) {
        const int k = kt + kq*8;
        s16x8 a[2];
        #pragma unroll
        for (int mf=0; mf<2; ++mf) {
            const int row = r0 + mf*16;
            if (AMODE == 0) {
                const float* s = (const float*)Aptr + (size_t)row*lda + k;
                float4 v0 = *(const float4*)s;
                float4 v1 = *(const float4*)(s+4);
                union { s16x8 v; unsigned short u[8]; } tc;
                tc.u[0]=f2bf(v0.x); tc.u[1]=f2bf(v0.y); tc.u[2]=f2bf(v0.z); tc.u[3]=f2bf(v0.w);
                tc.u[4]=f2bf(v1.x); tc.u[5]=f2bf(v1.y); tc.u[6]=f2bf(v1.z); tc.u[7]=f2bf(v1.w);
                a[mf] = tc.v;
            } else {
                const unsigned short* s = (const unsigned short*)Aptr + (size_t)row*lda + k;
                union { unsigned long long q[2]; s16x8 v; } tc;
                tc.q[0] = agu8(s);
                tc.q[1] = agu8(s + 4);
                a[mf] = tc.v;
            }
        }
        #pragma unroll
        for (int nf=0; nf<NF; ++nf) {
            s16x8 b = *(const s16x8*)&wtile[(nf*16+fr)*WSTR + k];
            acc[0][nf] = __builtin_amdgcn_mfma_f32_16x16x32_bf16(a[0], b, acc[0][nf], 0,0,0);
            acc[1][nf] = __builtin_amdgcn_mfma_f32_16x16x32_bf16(a[1], b, acc[1][nf], 0,0,0);
        }
    }
    #pragma unroll
    for (int nf=0; nf<NF; ++nf) {
        const int col = nf*16 + fr;
        const float bb = bias ? bias[col] : 0.f;
        #pragma unroll
        for (int mf=0; mf<2; ++mf) {
            const int row = w*32 + mf*16 + kq*4;
            #pragma unroll
            for (int r=0; r<4; ++r)
                agsf(&Cout[(size_t)(row+r)*ldc + col], acc[mf][nf][r] + bb);
        }
    }
}

// copy a [rows x 256] bf16 tile (row stride ld) into LDS (stride WSTR)
__device__ __forceinline__ void load_wtile(const unsigned short* __restrict__ src,
                                           int ld, unsigned short* dst, int rows, int tid)
{
    const int chunks = rows * 32;       // 8-elem (16B) chunks
    for (int cidx = tid; cidx < chunks; cidx += 256) {
        const int r = cidx >> 5, k8 = (cidx & 31) << 3;
        *(uint4*)&dst[r*WSTR + k8] = *(const uint4*)&src[(size_t)r*ld + k8];
    }
}

// =====================================================================
// prep kernels
// =====================================================================
__global__ __launch_bounds__(256) void k_prep_convert(
    const float* __restrict__ hyp_Wx, const float* __restrict__ hyp_Wh,
    const float* __restrict__ hyp_bx, const float* __restrict__ hyp_bh,
    const float* __restrict__ Wx, const float* __restrict__ Wh,
    unsigned short* __restrict__ wcat1bf, unsigned short* __restrict__ wxbf,
    unsigned short* __restrict__ whbf, float* __restrict__ bias1,
    float* __restrict__ act1f, float* __restrict__ c, float* __restrict__ ch,
    unsigned int* __restrict__ act1bf_zero, unsigned int* __restrict__ gcnt_zero)
{
    size_t i = (size_t)blockIdx.x*256 + threadIdx.x;
    if (i < 1572864u) {   // Wcat1 = [hyp_Wx | hyp_Wh], (1024,1536)
        int n = (int)(i / 1536), k = (int)(i % 1536);
        float v = (k < 1280) ? hyp_Wx[(size_t)n*1280 + k] : hyp_Wh[(size_t)n*256 + (k-1280)];
        wcat1bf[i] = f2bf(v); return;
    }
    i -= 1572864u;
    if (i < 1048576u) { wxbf[i] = f2bf(Wx[i]); return; }
    i -= 1048576u;
    if (i < 4194304u) { whbf[i] = f2bf(Wh[i]); return; }
    i -= 4194304u;
    if (i < 1024u) { bias1[i] = hyp_bx[i] + hyp_bh[i]; return; }
    i -= 1024u;
    if (i < 163840u) { act1f[i] = 0.f; return; }
    i -= 163840u;
    if (i < 131072u) { c[i] = 0.f; return; }
    i -= 131072u;
    if (i < 32768u) { ch[i] = 0.f; return; }
    i -= 32768u;
    if (i < 81920u) { act1bf_zero[i] = 0u; return; }
    i -= 81920u;
    if (i < 512u) { gcnt_zero[i] = 0u; return; }
}
#define PREP_TOTAL 7226880u

__global__ __launch_bounds__(128) void k_prep_wcomb(
    const float* __restrict__ zw_w, const float* __restrict__ zb,
    const float* __restrict__ alpha, const float* __restrict__ zbeta,
    float* __restrict__ wcombf32)
{
    int kk = blockIdx.z;
    const float* A = (kk < 8) ? (zw_w + (size_t)kk*65536) : (zb + (size_t)(kk-8)*65536);
    const float* Bm = (kk < 8) ? (alpha + (size_t)kk*262144) : (zbeta + (size_t)(kk-8)*262144);
    gemm_dev(A, 256, KSPLIT_NONE, A, 256, Bm, 1024, 0, nullptr,
             wcombf32 + (size_t)kk*262144, 1024, 256, 0, blockIdx.x, blockIdx.y);
}

__global__ __launch_bounds__(256) void k_prep_cvtcomb(
    const float* __restrict__ wcombf32, unsigned short* __restrict__ wcombbf)
{
    size_t i = (size_t)blockIdx.x*256 + threadIdx.x;
    if (i >= 3145728u) return;
    int kk = (int)(i / 262144u);
    int r  = (int)(i % 262144u);
    int n = r / 256, k = r % 256;
    wcombbf[i] = f2bf(wcombf32[(size_t)kk*262144 + (size_t)k*1024 + n]);
}

__global__ __launch_bounds__(256) void k_prep_bcomb(
    const float* __restrict__ zw_b, const float* __restrict__ alpha,
    float* __restrict__ bcomb)
{
    int k = blockIdx.x;
    int n = blockIdx.y*256 + threadIdx.x;
    float s = 0.f;
    for (int p=0;p<256;++p)
        s += zw_b[k*256+p] * alpha[(size_t)k*262144 + (size_t)p*1024 + n];
    bcomb[(size_t)k*1024 + n] = s;
}

// =====================================================================
// reductions / cell bodies
// =====================================================================
__device__ __forceinline__ void breduce2(float& a, float& b, volatile float* buf, int tid){
    #pragma unroll
    for (int off = 32; off > 0; off >>= 1) { a += __shfl_xor(a, off); b += __shfl_xor(b, off); }
    __syncthreads();
    if ((tid & 63) == 0) { buf[(tid>>6)*2] = a; buf[(tid>>6)*2+1] = b; }
    __syncthreads();
    a = buf[0] + buf[2] + buf[4] + buf[6];
    b = buf[1] + buf[3] + buf[5] + buf[7];
}

// ---- coop-path cells: agent loads of partials, packed bf16 agent stores ----
__device__ __forceinline__ void hyper_cell6(
    int b, int tid, volatile float* cbuf,
    const float* __restrict__ gpart, const float* __restrict__ bias1,
    const float* __restrict__ lna_g, const float* __restrict__ lna_b,
    const float* __restrict__ ln_g, const float* __restrict__ ln_b,
    float* __restrict__ ch, unsigned short* __restrict__ act1bf)
{
    float v[4];
    #pragma unroll
    for (int g=0; g<4; ++g){
        size_t idx = (size_t)b*1024 + g*256 + tid;
        v[g] = agf(&gpart[idx]) + agf(&gpart[131072+idx]) + agf(&gpart[262144+idx])
             + agf(&gpart[393216+idx]) + agf(&gpart[524288+idx]) + agf(&gpart[655360+idx])
             + bias1[g*256 + tid];
    }
    #pragma unroll
    for (int g=0; g<4; ++g){
        float s = v[g], ss = v[g]*v[g];
        breduce2(s, ss, cbuf, tid);
        float m = s * (1.f/256.f);
        float var = ss * (1.f/256.f) - m*m;
        v[g] = (v[g]-m)*rsqrtf(var + EPS)*lna_g[g*256+tid] + lna_b[g*256+tid];
    }
    float chp = ch[b*256 + tid];
    float cn = sigm(v[1])*chp + sigm(v[0])*tanhf(v[2]);
    float s = cn, ss = cn*cn;
    breduce2(s, ss, cbuf, tid);
    float m = s*(1.f/256.f);
    float var = ss*(1.f/256.f) - m*m;
    float hn = sigm(v[3]) * tanhf((cn-m)*rsqrtf(var + EPS)*ln_g[tid] + ln_b[tid]);
    ch[b*256 + tid] = cn;
    // packed bf16 agent store (pairs of adjacent tids, same wave)
    unsigned hb = f2bf(hn);
    unsigned other = __shfl_down(hb, 1);
    if (!(tid & 1))
        agsu((unsigned*)(act1bf + (size_t)b*1280 + 1024 + tid), hb | (other << 16));
}

__device__ __forceinline__ void main_cell2(
    int b, int tid, volatile float* cbuf,
    const float* __restrict__ bias4,
    const float* __restrict__ lna_g, const float* __restrict__ lna_b,
    const float* __restrict__ ln_g, const float* __restrict__ ln_b,
    const float* __restrict__ xgbuf, const float* __restrict__ hgpart,
    const float* __restrict__ scb,
    float* __restrict__ c, unsigned short* __restrict__ act1bf,
    float* __restrict__ hfc)
{
    float gn[4][4];
    #pragma unroll
    for (int k=0;k<4;++k){
        float pre[4]; float s=0.f, ss=0.f;
        #pragma unroll
        for (int j=0;j<4;++j){
            int h = j*256 + tid;
            int n = k*1024 + h;
            size_t bh = (size_t)b*1024 + h;
            size_t bn = (size_t)b*4096 + n;
            float xgv = agf(&xgbuf[bn]);
            float hgv = agf(&hgpart[bn]) + agf(&hgpart[524288+bn])
                      + agf(&hgpart[1048576+bn]) + agf(&hgpart[1572864+bn]);
            float p = agf(&scb[(size_t)k*131072 + bh])*xgv
                    + agf(&scb[(size_t)(4+k)*131072 + bh])*hgv
                    + bias4[n] + agf(&scb[(size_t)(8+k)*131072 + bh]);
            pre[j] = p; s += p; ss += p*p;
        }
        breduce2(s, ss, cbuf, tid);
        float m = s*(1.f/1024.f);
        float var = ss*(1.f/1024.f) - m*m;
        float rs = rsqrtf(var + EPS);
        #pragma unroll
        for (int j=0;j<4;++j){
            int h=j*256+tid, n=k*1024+h;
            gn[k][j] = (pre[j]-m)*rs*lna_g[n] + lna_b[n];
        }
    }
    float cnv[4]; float s=0.f, ss=0.f;
    #pragma unroll
    for (int j=0;j<4;++j){
        int h=j*256+tid;
        float cv = c[(size_t)b*1024+h];
        float x = sigm(gn[2][j])*cv + sigm(gn[0][j])*tanhf(gn[1][j]);
        cnv[j]=x; s+=x; ss+=x*x;
    }
    breduce2(s, ss, cbuf, tid);
    float m=s*(1.f/1024.f);
    float var=ss*(1.f/1024.f)-m*m;
    float rs=rsqrtf(var + EPS);
    #pragma unroll
    for (int j=0;j<4;++j){
        int h=j*256+tid;
        float hv = sigm(gn[3][j])*tanhf((cnv[j]-m)*rs*ln_g[h] + ln_b[h]);
        c[(size_t)b*1024+h] = cnv[j];
        hfc[(size_t)b*1024 + h] = hv;
        unsigned hb = f2bf(hv);
        unsigned other = __shfl_down(hb, 1);
        if (!(tid & 1))
            agsu((unsigned*)(act1bf + (size_t)b*1280 + h), hb | (other << 16));
    }
}

// ---- fallback cells (f32 activations, 4-way gpart) ----
__device__ __forceinline__ void hyper_cell_body(
    const float* __restrict__ lna_g, const float* __restrict__ lna_b,
    const float* __restrict__ ln_g, const float* __restrict__ ln_b,
    const float* __restrict__ gpart, const float* __restrict__ bias1,
    float* __restrict__ ch, float* __restrict__ act1, int b, int tid)
{
    __shared__ float buf[8];
    float v[4];
    #pragma unroll
    for (int g=0; g<4; ++g){
        int idx = b*1024 + g*256 + tid;
        v[g] = gpart[idx] + gpart[131072 + idx] + gpart[262144 + idx] + gpart[393216 + idx]
             + bias1[g*256 + tid];
    }
    #pragma unroll
    for (int g=0; g<4; ++g){
        float s = v[g], ss = v[g]*v[g];
        breduce2(s, ss, buf, tid);
        float m = s * (1.f/256.f);
        float var = ss * (1.f/256.f) - m*m;
        v[g] = (v[g]-m)*rsqrtf(var + EPS)*lna_g[g*256+tid] + lna_b[g*256+tid];
    }
    float chp = ch[b*256 + tid];
    float cn = sigm(v[1])*chp + sigm(v[0])*tanhf(v[2]);
    float s = cn, ss = cn*cn;
    breduce2(s, ss, buf, tid);
    float m = s*(1.f/256.f);
    float var = ss*(1.f/256.f) - m*m;
    float hn = sigm(v[3]) * tanhf((cn-m)*rsqrtf(var + EPS)*ln_g[tid] + ln_b[tid]);
    ch[b*256 + tid] = cn;
    act1[b*1280 + 1024 + tid] = hn;
}

__device__ __forceinline__ void main_cell_body(
    const float* __restrict__ bias4,
    const float* __restrict__ lna_g, const float* __restrict__ lna_b,
    const float* __restrict__ ln_g, const float* __restrict__ ln_b,
    const float* __restrict__ xghg, const float* __restrict__ scb,
    float* __restrict__ c, float* __restrict__ act1, int b, int tid)
{
    __shared__ float buf[8];
    float gn[4][4];
    #pragma unroll
    for (int k=0;k<4;++k){
        float pre[4]; float s=0.f, ss=0.f;
        #pragma unroll
        for (int j=0;j<4;++j){
            int h = j*256 + tid;
            int n = k*1024 + h;
            int bh = b*1024 + h;
            float xgv = xghg[b*4096 + n];
            float hgv = xghg[524288 + b*4096 + n];
            float p = scb[k*131072 + bh]*xgv + scb[(4+k)*131072 + bh]*hgv
                    + bias4[n] + scb[(8+k)*131072 + bh];
            pre[j] = p; s += p; ss += p*p;
        }
        breduce2(s, ss, buf, tid);
        float m = s*(1.f/1024.f);
        float var = ss*(1.f/1024.f) - m*m;
        float rs = rsqrtf(var + EPS);
        #pragma unroll
        for (int j=0;j<4;++j){
            int h=j*256+tid, n=k*1024+h;
            gn[k][j] = (pre[j]-m)*rs*lna_g[n] + lna_b[n];
        }
    }
    float cnv[4]; float s=0.f, ss=0.f;
    #pragma unroll
    for (int j=0;j<4;++j){
        int h=j*256+tid;
        float cv = c[b*1024+h];
        float x = sigm(gn[2][j])*cv + sigm(gn[0][j])*tanhf(gn[1][j]);
        cnv[j]=x; s+=x; ss+=x*x;
    }
    breduce2(s, ss, buf, tid);
    float m=s*(1.f/1024.f);
    float var=ss*(1.f/1024.f)-m*m;
    float rs=rsqrtf(var + EPS);
    #pragma unroll
    for (int j=0;j<4;++j){
        int h=j*256+tid;
        float hv = sigm(gn[3][j])*tanhf((cnv[j]-m)*rs*ln_g[h] + ln_b[h]);
        c[b*1024+h] = cnv[j];
        act1[b*1280 + h] = hv;
    }
}

// =====================================================================
// fallback step kernels
// =====================================================================
__global__ __launch_bounds__(256) void k_step1(
    const float* __restrict__ xt, const float* __restrict__ act1,
    const unsigned short* __restrict__ wcat1bf,
    const unsigned short* __restrict__ wxbf, const unsigned short* __restrict__ whbf,
    float* __restrict__ gpart, float* __restrict__ xghg)
{
    int bid = blockIdx.x;
    if (bid < 128) {
        int sp = bid >> 5, r = bid & 31;
        gemm_mfma(xt, 256, 256, act1, 1280, wcat1bf, 1536, nullptr,
                  gpart + (size_t)sp*131072, 1024, 384, sp*384, r >> 3, r & 7);
    } else if (bid < 256) {
        int r = bid - 128;
        gemm_mfma(xt, 256, KSPLIT_NONE, xt, 256, wxbf, 256, nullptr,
                  xghg, 4096, 256, 0, r >> 5, r & 31);
    } else {
        int r = bid - 256;
        gemm_mfma(act1, 1280, KSPLIT_NONE, act1, 1280, whbf, 1024, nullptr,
                  xghg + 524288, 4096, 1024, 0, r >> 5, r & 31);
    }
}

__global__ __launch_bounds__(256) void k_step2(
    const float* __restrict__ act1, const unsigned short* __restrict__ wcombbf,
    const float* __restrict__ bcomb, float* __restrict__ scb)
{
    int bid = blockIdx.x;
    int kk = bid >> 5, r = bid & 31;
    const float* bias = (kk < 8) ? (bcomb + (size_t)kk*1024) : nullptr;
    gemm_mfma(act1 + 1024, 1280, KSPLIT_NONE, act1 + 1024, 1280,
              wcombbf + (size_t)kk*262144, 256, bias,
              scb + (size_t)kk*131072, 1024, 256, 0, r >> 3, r & 7);
}

__global__ __launch_bounds__(256) void k_hyper_cell(
    const float* __restrict__ lna_g, const float* __restrict__ lna_b,
    const float* __restrict__ ln_g, const float* __restrict__ ln_b,
    const float* __restrict__ gpart, const float* __restrict__ bias1,
    float* __restrict__ ch, float* __restrict__ act1)
{
    hyper_cell_body(lna_g, lna_b, ln_g, ln_b, gpart, bias1, ch, act1,
                    blockIdx.x, threadIdx.x);
}

__global__ __launch_bounds__(256) void k_main_cell(
    const float* __restrict__ bias4,
    const float* __restrict__ lna_g, const float* __restrict__ lna_b,
    const float* __restrict__ ln_g, const float* __restrict__ ln_b,
    const float* __restrict__ xghg, const float* __restrict__ scb,
    float* __restrict__ c, float* __restrict__ act1)
{
    main_cell_body(bias4, lna_g, lna_b, ln_g, ln_b, xghg, scb, c, act1,
                   blockIdx.x, threadIdx.x);
}

// =====================================================================
// persistent kernel v3: weights in LDS + fence-free agent-scope phases
// 512 blocks x 256 threads, 2 blocks/CU. No grid.sync, no L2 flushes.
// =====================================================================
__global__ __launch_bounds__(256, 2) void k_persist3(
    const float* __restrict__ x,
    const unsigned short* __restrict__ wcat1bf,
    const unsigned short* __restrict__ wxbf,
    const unsigned short* __restrict__ whbf,
    const unsigned short* __restrict__ wcombbf,
    const float* __restrict__ bcomb, const float* __restrict__ bias1,
    const float* __restrict__ bias4,
    const float* __restrict__ lna_g, const float* __restrict__ lna_b,
    const float* __restrict__ ln_g, const float* __restrict__ ln_b,
    const float* __restrict__ hlna_g, const float* __restrict__ hlna_b,
    const float* __restrict__ hln_g, const float* __restrict__ hln_b,
    float* __restrict__ gpart, float* __restrict__ hgpart,
    float* __restrict__ xgbuf, float* __restrict__ scb,
    unsigned short* __restrict__ act1bf, float* __restrict__ hfc,
    float* __restrict__ c, float* __restrict__ ch,
    unsigned* __restrict__ gcnt)
{
    const int bid = blockIdx.x, tid = threadIdx.x;
    const int lane = tid & 63, w = tid >> 6;
    __shared__ __align__(16) unsigned short wlds[25344];  // [64][264] + [32][264]
    __shared__ float cbuf[8];

    // ---- one-time weight preload into LDS ----
    if (bid < 96) {
        load_wtile(wcat1bf + (size_t)((bid & 15)*64)*1536 + (bid >> 4)*256,
                   1536, wlds, 64, tid);
    } else if (bid < 352) {
        int h_ = bid - 96;
        load_wtile(whbf + (size_t)((h_ >> 2)*64)*1024 + (h_ & 3)*256,
                   1024, wlds, 64, tid);
    } else if (bid < 416) {
        load_wtile(wxbf + (size_t)(bid - 352)*64*256, 256, wlds, 64, tid);
    }
    if (bid < 384) {
        int kk = bid >> 5, mt = bid & 31;
        load_wtile(wcombbf + (size_t)kk*262144 + (size_t)(mt*32)*256,
                   256, wlds + 16896, 32, tid);
    }
    __syncthreads();

    unsigned phase = 0;
    for (int t = 0; t < T_STEPS; ++t) {
        const float* xt = x + (size_t)t*BATCH*DIN;

        // ---- phase A: hyper gates g1 (6 pure K-splits) ----
        if (bid < 96) {
            int nt = bid & 15, sp = bid >> 4;
            float* outp = gpart + (size_t)sp*131072 + nt*64;
            if (sp == 0)
                gemm_ws<4,0>(xt, 256, wlds, nullptr, outp, 1024, lane, w);
            else
                gemm_ws<4,2>(act1bf + (sp-1)*256, 1280, wlds, nullptr, outp, 1024, lane, w);
        }
        gbar(gcnt, ++phase, bid, tid);

        // ---- phase B: hg (split-K4) + xg + hyper cell ----
        if (bid >= 96 && bid < 352) {
            int h_ = bid - 96, nt = h_ >> 2, sp = h_ & 3;
            gemm_ws<4,2>(act1bf + sp*256, 1280, wlds, nullptr,
                         hgpart + (size_t)sp*524288 + nt*64, 4096, lane, w);
        } else if (bid >= 352 && bid < 416) {
            gemm_ws<4,0>(xt, 256, wlds, nullptr,
                         xgbuf + (bid - 352)*64, 4096, lane, w);
        } else {
            int row = (bid >= 416) ? (bid - 416) : (bid < 32 ? 96 + bid : -1);
            if (row >= 0)
                hyper_cell6(row, tid, cbuf, gpart, bias1,
                            hlna_g, hlna_b, hln_g, hln_b, ch, act1bf);
        }
        gbar(gcnt, ++phase, bid, tid);

        // ---- phase C: 12 x (hyp @ Wcomb[k]) ----
        if (bid < 384) {
            int kk = bid >> 5, mt = bid & 31;
            const float* bp = (kk < 8) ? (bcomb + (size_t)kk*1024 + mt*32) : nullptr;
            gemm_ws<2,2>(act1bf + 1024, 1280, wlds + 16896, bp,
                         scb + (size_t)kk*131072 + mt*32, 1024, lane, w);
        }
        gbar(gcnt, ++phase, bid, tid);

        // ---- phase D: main cell ----
        if (bid < 128)
            main_cell2(bid, tid, cbuf, bias4, lna_g, lna_b, ln_g, ln_b,
                       xgbuf, hgpart, scb, c, act1bf, hfc);
        gbar(gcnt, ++phase, bid, tid);
    }
}

__global__ __launch_bounds__(128) void k_fc2(
    const float* __restrict__ fcW, const float* __restrict__ fcb,
    const float* __restrict__ hsrc, int ldh, float* __restrict__ out)
{
    int b = blockIdx.x, o = threadIdx.x;
    const float* h = hsrc + (size_t)b*ldh;
    float s = fcb[o];
    for (int k=0;k<1024;++k) s += h[k]*fcW[(size_t)o*1024 + k];
    out[b*OUTN + o] = s;
}

// =====================================================================
// launch
// =====================================================================
extern "C" void kernel_launch(void* const* d_in, const int* in_sizes, int n_in,
                              void* d_out, int out_size, void* d_ws, size_t ws_size,
                              hipStream_t stream)
{
    const float* x        = (const float*)d_in[0];
    const float* Wx       = (const float*)d_in[1];
    const float* Wh       = (const float*)d_in[2];
    const float* bias     = (const float*)d_in[3];
    const float* lna_g    = (const float*)d_in[4];
    const float* lna_b    = (const float*)d_in[5];
    const float* ln_g     = (const float*)d_in[6];
    const float* ln_b     = (const float*)d_in[7];
    const float* zb       = (const float*)d_in[8];
    const float* zbeta    = (const float*)d_in[9];
    const float* zw_w     = (const float*)d_in[10];
    const float* zw_b     = (const float*)d_in[11];
    const float* alpha    = (const float*)d_in[12];
    const float* hyp_Wx   = (const float*)d_in[13];
    const float* hyp_bx   = (const float*)d_in[14];
    const float* hyp_Wh   = (const float*)d_in[15];
    const float* hyp_bh   = (const float*)d_in[16];
    const float* hlna_g   = (const float*)d_in[17];
    const float* hlna_b   = (const float*)d_in[18];
    const float* hln_g    = (const float*)d_in[19];
    const float* hln_b    = (const float*)d_in[20];
    const float* fcW      = (const float*)d_in[21];
    const float* fcb      = (const float*)d_in[22];
    float* out = (float*)d_out;

    // ---- workspace carve (elements) ----
    unsigned short* wcat1bf = (unsigned short*)d_ws;          // 1572864
    unsigned short* wxbf    = wcat1bf + 1572864;              // 1048576
    unsigned short* whbf    = wxbf + 1048576;                 // 4194304
    unsigned short* wcombbf = whbf + 4194304;                 // 3145728
    unsigned short* act1bf  = wcombbf + 3145728;              // 163840 (bf16 [h|hh])
    float* fbase = (float*)(act1bf + 163840);
    float* bcomb = fbase;                                     // 8192
    float* bias1 = bcomb + 8192;                              // 1024
    float* hfc   = bias1 + 1024;                              // 131072 (f32 h for fc)
    float* c     = hfc + 131072;                              // 131072
    float* ch    = c + 131072;                                // 32768
    float* act1o = ch + 32768;                                // 163840 (f32, fallback)
    float* gpart = act1o + 163840;                            // 786432 (6 x 131072)
    float* hgpart= gpart + 786432;                            // 2097152 (4 x 524288)
    float* xgbuf = hgpart + 2097152;                          // 524288
    float* scb   = xgbuf + 524288;                            // 1572864 (12 x 131072)
    unsigned* gcnt = (unsigned*)(scb + 1572864);              // 512 uints (16 lines)
    float* wcombf32 = gpart;                                  // prep-time alias

    // ---- prep ----
    k_prep_convert<<<(PREP_TOTAL + 255)/256, 256, 0, stream>>>(
        hyp_Wx, hyp_Wh, hyp_bx, hyp_bh, Wx, Wh,
        wcat1bf, wxbf, whbf, bias1, act1o, c, ch,
        (unsigned int*)act1bf, gcnt);
    k_prep_wcomb<<<dim3(8,16,12), 128, 0, stream>>>(zw_w, zb, alpha, zbeta, wcombf32);
    k_prep_bcomb<<<dim3(8,4), 256, 0, stream>>>(zw_b, alpha, bcomb);
    k_prep_cvtcomb<<<(3145728 + 255)/256, 256, 0, stream>>>(wcombf32, wcombbf);

    // ---- cooperative capability gate (host-side, capture-safe) ----
    static int use_coop = -1;
    if (use_coop < 0) {
        use_coop = 0;
        int dev = 0;
        if (hipGetDevice(&dev) == hipSuccess) {
            hipDeviceProp_t prop;
            if (hipGetDeviceProperties(&prop, dev) == hipSuccess &&
                prop.cooperativeLaunch) {
                int occ = 0;
                if (hipOccupancyMaxActiveBlocksPerMultiprocessor(
                        &occ, (const void*)k_persist3, 256, 0) == hipSuccess &&
                    occ >= 2 && occ * prop.multiProcessorCount >= NBLK) {
                    use_coop = 1;
                }
            }
        }
    }

    int coop_launched = 0;
    if (use_coop) {
        void* cargs[] = {
            (void*)&x, (void*)&wcat1bf, (void*)&wxbf, (void*)&whbf, (void*)&wcombbf,
            (void*)&bcomb, (void*)&bias1, (void*)&bias,
            (void*)&lna_g, (void*)&lna_b, (void*)&ln_g, (void*)&ln_b,
            (void*)&hlna_g, (void*)&hlna_b, (void*)&hln_g, (void*)&hln_b,
            (void*)&gpart, (void*)&hgpart, (void*)&xgbuf, (void*)&scb,
            (void*)&act1bf, (void*)&hfc, (void*)&c, (void*)&ch, (void*)&gcnt
        };
        hipError_t e = hipLaunchCooperativeKernel((const void*)k_persist3,
                                                  dim3(NBLK), dim3(256),
                                                  cargs, 0u, stream);
        if (e == hipSuccess) {
            coop_launched = 1;
        } else {
            (void)hipGetLastError();
            use_coop = 0;
        }
    }

    if (!coop_launched) {
        // fallback: old 4-launch structure
        float* xghg = hgpart;
        for (int t = 0; t < T_STEPS; ++t) {
            const float* xt = x + (size_t)t*BATCH*DIN;
            k_step1<<<384, 256, 0, stream>>>(xt, act1o, wcat1bf, wxbf, whbf, gpart, xghg);
            k_hyper_cell<<<BATCH, 256, 0, stream>>>(hlna_g, hlna_b, hln_g, hln_b,
                                                    gpart, bias1, ch, act1o);
            k_step2<<<384, 256, 0, stream>>>(act1o, wcombbf, bcomb, scb);
            k_main_cell<<<BATCH, 256, 0, stream>>>(bias, lna_g, lna_b, ln_g, ln_b,
                                                   xghg, scb, c, act1o);
        }
        k_fc2<<<BATCH, 128, 0, stream>>>(fcW, fcb, act1o, 1280, out);
        return;
    }

    // ---- final projection (coop path) ----
    k_fc2<<<BATCH, 128, 0, stream>>>(fcW, fcb, hfc, 1024, out);
}

// Round 4
// 34072.879 us; speedup vs baseline: 1.0061x; 1.0033x over previous
//
#include <hip/hip_runtime.h>
#include <math.h>

// ---------------- problem dims ----------------
#define T_STEPS 512
#define BATCH   128
#define DIN     256
#define HMAIN   1024
#define HHYP    256
#define OUTN    128
#define EPS     1e-3f

#define KSPLIT_NONE (1<<30)
#define NBLK 512

typedef __attribute__((ext_vector_type(4))) float f32x4;
typedef __attribute__((ext_vector_type(8))) short s16x8;

__device__ __forceinline__ float sigm(float x){ return 1.f/(1.f + expf(-x)); }

__device__ __forceinline__ unsigned short f2bf(float f){
    union { float f; unsigned u; } x; x.f = f;
    unsigned r = x.u + 0x7FFFu + ((x.u >> 16) & 1u);   // RNE
    return (unsigned short)(r >> 16);
}

// ---- agent-scope (device-coherent, LLC-routed) access helpers ----
__device__ __forceinline__ float agf(const float* p){
    return __hip_atomic_load(const_cast<float*>(p), __ATOMIC_RELAXED, __HIP_MEMORY_SCOPE_AGENT);
}
__device__ __forceinline__ unsigned long long agu8(const void* p){
    return __hip_atomic_load(const_cast<unsigned long long*>((const unsigned long long*)p),
                             __ATOMIC_RELAXED, __HIP_MEMORY_SCOPE_AGENT);
}
__device__ __forceinline__ void agsf(float* p, float v){
    __hip_atomic_store(p, v, __ATOMIC_RELAXED, __HIP_MEMORY_SCOPE_AGENT);
}
__device__ __forceinline__ void agsu(unsigned* p, unsigned v){
    __hip_atomic_store(p, v, __ATOMIC_RELAXED, __HIP_MEMORY_SCOPE_AGENT);
}

// =====================================================================
// custom grid barrier: NO L2 flush. All cross-phase data is agent-scope
// write-through, so visibility only needs vmcnt(0) (from __syncthreads)
// before the arrive-add. 16 counter lines (128B apart) cut contention.
// =====================================================================
__device__ __forceinline__ void gbar(unsigned* cnt, unsigned phase, int bid, int tid){
    __syncthreads();                       // all threads' sc1 stores drained
    if (tid < 16){
        if (tid == (bid & 15))
            __hip_atomic_fetch_add(&cnt[tid*32], 1u, __ATOMIC_RELAXED, __HIP_MEMORY_SCOPE_AGENT);
        const unsigned tg = phase * (NBLK/16);
        while (__hip_atomic_load(&cnt[tid*32], __ATOMIC_RELAXED, __HIP_MEMORY_SCOPE_AGENT) < tg)
            __builtin_amdgcn_s_sleep(4);
    }
    __syncthreads();
}

// =====================================================================
// fp32 tiled GEMM (prep only): tile 32x64, KT=32, 128 thr, 4x4 micro
// =====================================================================
#define BM 32
#define BN 64
#define KT 32
__device__ void gemm_dev(const float* __restrict__ A1, int lda1, int ksplit,
                         const float* __restrict__ A2, int lda2,
                         const float* __restrict__ Bp, int ldb, int b_nk,
                         const float* __restrict__ bias,
                         float* __restrict__ C, int ldc,
                         int K, int k0, int mtile, int ntile)
{
    __shared__ __align__(16) float As[KT][BM+4];
    __shared__ __align__(16) float Bs[KT][BN+4];
    const int tid = threadIdx.x;
    const int mt = tid >> 4, nt = tid & 15;
    const int m0g = mtile*BM, n0g = ntile*BN;
    float acc[4][4];
    #pragma unroll
    for (int i=0;i<4;++i) { acc[i][0]=0;acc[i][1]=0;acc[i][2]=0;acc[i][3]=0; }
    for (int kt = 0; kt < K; kt += KT) {
        __syncthreads();
        #pragma unroll
        for (int i=0;i<8;++i){
            int e = tid + i*128;
            int m = e >> 5, k = e & 31;
            int gk = k0 + kt + k, gm = m0g + m;
            float v = (gk < ksplit) ? A1[(size_t)gm*lda1 + gk]
                                    : A2[(size_t)gm*lda2 + (gk - ksplit)];
            As[k][m] = v;
        }
        if (b_nk) {
            #pragma unroll
            for (int i=0;i<16;++i){
                int e = tid + i*128;
                int n = e >> 5, k = e & 31;
                Bs[k][n] = Bp[(size_t)(n0g + n)*ldb + (k0 + kt + k)];
            }
        } else {
            #pragma unroll
            for (int i=0;i<16;++i){
                int e = tid + i*128;
                int k = e >> 6, n = e & 63;
                Bs[k][n] = Bp[(size_t)(k0 + kt + k)*ldb + (n0g + n)];
            }
        }
        __syncthreads();
        #pragma unroll
        for (int k=0;k<KT;++k){
            float4 av = *(const float4*)(&As[k][4*mt]);
            float4 bv = *(const float4*)(&Bs[k][4*nt]);
            acc[0][0]+=av.x*bv.x; acc[0][1]+=av.x*bv.y; acc[0][2]+=av.x*bv.z; acc[0][3]+=av.x*bv.w;
            acc[1][0]+=av.y*bv.x; acc[1][1]+=av.y*bv.y; acc[1][2]+=av.y*bv.z; acc[1][3]+=av.y*bv.w;
            acc[2][0]+=av.z*bv.x; acc[2][1]+=av.z*bv.y; acc[2][2]+=av.z*bv.z; acc[2][3]+=av.z*bv.w;
            acc[3][0]+=av.w*bv.x; acc[3][1]+=av.w*bv.y; acc[3][2]+=av.w*bv.z; acc[3][3]+=av.w*bv.w;
        }
    }
    #pragma unroll
    for (int i=0;i<4;++i){
        int gm = m0g + 4*mt + i;
        #pragma unroll
        for (int j=0;j<4;++j){
            int gn = n0g + 4*nt + j;
            float v = acc[i][j];
            if (bias) v += bias[gn];
            C[(size_t)gm*ldc + gn] = v;
        }
    }
}

// =====================================================================
// OLD bf16 MFMA GEMM (fallback path only)
// =====================================================================
#define ASTR 40
__device__ void gemm_mfma(const float* __restrict__ A1, int lda1, int ksplit,
                          const float* __restrict__ A2, int lda2,
                          const unsigned short* __restrict__ B, int ldb,
                          const float* __restrict__ bias,
                          float* __restrict__ C, int ldc,
                          int K, int k0, int mtile, int ntile)
{
    __shared__ __align__(16) unsigned short As[32*ASTR];
    __shared__ __align__(16) unsigned short Bs[128*ASTR];
    const int tid = threadIdx.x;
    const int lane = tid & 63, w = tid >> 6;
    const int wm = (w >> 1) * 16, wn = (w & 1) * 64;
    const int fr = lane & 15, koff = (lane >> 4) * 8;
    const int m0g = mtile*32, n0g = ntile*128;

    f32x4 acc[4];
    #pragma unroll
    for (int j=0;j<4;++j) acc[j] = (f32x4){0.f,0.f,0.f,0.f};

    const int arow = tid >> 3, akc = (tid & 7) * 4;
    for (int kt = 0; kt < K; kt += 32) {
        __syncthreads();
        {
            int gk = k0 + kt + akc;
            int gm = m0g + arow;
            const float* src = (gk < ksplit) ? (A1 + (size_t)gm*lda1 + gk)
                                             : (A2 + (size_t)gm*lda2 + (gk - ksplit));
            float4 v = *(const float4*)src;
            unsigned short* d = &As[arow*ASTR + akc];
            d[0] = f2bf(v.x); d[1] = f2bf(v.y); d[2] = f2bf(v.z); d[3] = f2bf(v.w);
        }
        #pragma unroll
        for (int i=0;i<4;++i){
            int e = tid + i*256;
            int n = e >> 3, kc = (e & 7) * 4;
            ushort4 bv = *(const ushort4*)(B + (size_t)(n0g + n)*ldb + (k0 + kt + kc));
            unsigned short* d = &Bs[n*ASTR + kc];
            d[0] = bv.x; d[1] = bv.y; d[2] = bv.z; d[3] = bv.w;
        }
        __syncthreads();
        s16x8 af = *(const s16x8*)&As[(wm + fr)*ASTR + koff];
        #pragma unroll
        for (int j=0;j<4;++j){
            s16x8 bf = *(const s16x8*)&Bs[(wn + j*16 + fr)*ASTR + koff];
            acc[j] = __builtin_amdgcn_mfma_f32_16x16x32_bf16(af, bf, acc[j], 0, 0, 0);
        }
    }
    #pragma unroll
    for (int j=0;j<4;++j){
        int gn = n0g + wn + j*16 + fr;
        float bb = bias ? bias[gn] : 0.f;
        #pragma unroll
        for (int r=0;r<4;++r){
            int gm = m0g + wm + (lane >> 4)*4 + r;
            C[(size_t)gm*ldc + gn] = acc[j][r] + bb;
        }
    }
}

// =====================================================================
// weights-in-LDS GEMM: M=128 (full batch), N = NF*16, K=256 fixed.
// AMODE 0: A is plain f32 (read-only input xt), converted to bf16.
// AMODE 2: A is bf16, agent-coherent (activations).
// C stores are agent-coherent. No __syncthreads inside.
// =====================================================================
#define WSTR 264
template<int NF, int AMODE>
__device__ __forceinline__ void gemm_ws(
    const void* __restrict__ Aptr, int lda,            // elements of src type
    const unsigned short* wtile,                       // LDS tile [NF*16][WSTR]
    const float* __restrict__ bias,                    // local col bias or null
    float* __restrict__ Cout, int ldc,
    int lane, int w)
{
    const int fr = lane & 15, kq = lane >> 4;
    f32x4 acc[2][NF];
    #pragma unroll
    for (int mf=0; mf<2; ++mf)
        #pragma unroll
        for (int nf=0; nf<NF; ++nf) acc[mf][nf] = (f32x4){0.f,0.f,0.f,0.f};
    const int r0 = w*32 + fr;
    #pragma unroll
    for (int kt=0; kt<256; kt+=32) {
        const int k = kt + kq*8;
        s16x8 a[2];
        #pragma unroll
        for (int mf=0; mf<2; ++mf) {
            const int row = r0 + mf*16;
            if (AMODE == 0) {
                const float* s = (const float*)Aptr + (size_t)row*lda + k;
                float4 v0 = *(const float4*)s;
                float4 v1 = *(const float4*)(s+4);
                union { s16x8 v; unsigned short u[8]; } tc;
                tc.u[0]=f2bf(v0.x); tc.u[1]=f2bf(v0.y); tc.u[2]=f2bf(v0.z); tc.u[3]=f2bf(v0.w);
                tc.u[4]=f2bf(v1.x); tc.u[5]=f2bf(v1.y); tc.u[6]=f2bf(v1.z); tc.u[7]=f2bf(v1.w);
                a[mf] = tc.v;
            } else {
                const unsigned short* s = (const unsigned short*)Aptr + (size_t)row*lda + k;
                union { unsigned long long q[2]; s16x8 v; } tc;
                tc.q[0] = agu8(s);
                tc.q[1] = agu8(s + 4);
                a[mf] = tc.v;
            }
        }
        #pragma unroll
        for (int nf=0; nf<NF; ++nf) {
            s16x8 b = *(const s16x8*)&wtile[(nf*16+fr)*WSTR + k];
            acc[0][nf] = __builtin_amdgcn_mfma_f32_16x16x32_bf16(a[0], b, acc[0][nf], 0,0,0);
            acc[1][nf] = __builtin_amdgcn_mfma_f32_16x16x32_bf16(a[1], b, acc[1][nf], 0,0,0);
        }
    }
    #pragma unroll
    for (int nf=0; nf<NF; ++nf) {
        const int col = nf*16 + fr;
        const float bb = bias ? bias[col] : 0.f;
        #pragma unroll
        for (int mf=0; mf<2; ++mf) {
            const int row = w*32 + mf*16 + kq*4;
            #pragma unroll
            for (int r=0; r<4; ++r)
                agsf(&Cout[(size_t)(row+r)*ldc + col], acc[mf][nf][r] + bb);
        }
    }
}

// copy a [rows x 256] bf16 tile (row stride ld) into LDS (stride WSTR)
__device__ __forceinline__ void load_wtile(const unsigned short* __restrict__ src,
                                           int ld, unsigned short* dst, int rows, int tid)
{
    const int chunks = rows * 32;       // 8-elem (16B) chunks
    for (int cidx = tid; cidx < chunks; cidx += 256) {
        const int r = cidx >> 5, k8 = (cidx & 31) << 3;
        *(uint4*)&dst[r*WSTR + k8] = *(const uint4*)&src[(size_t)r*ld + k8];
    }
}

// =====================================================================
// prep kernels
// =====================================================================
__global__ __launch_bounds__(256) void k_prep_convert(
    const float* __restrict__ hyp_Wx, const float* __restrict__ hyp_Wh,
    const float* __restrict__ hyp_bx, const float* __restrict__ hyp_bh,
    const float* __restrict__ Wx, const float* __restrict__ Wh,
    unsigned short* __restrict__ wcat1bf, unsigned short* __restrict__ wxbf,
    unsigned short* __restrict__ whbf, float* __restrict__ bias1,
    float* __restrict__ act1f, float* __restrict__ c, float* __restrict__ ch,
    unsigned int* __restrict__ act1bf_zero, unsigned int* __restrict__ gcnt_zero)
{
    size_t i = (size_t)blockIdx.x*256 + threadIdx.x;
    if (i < 1572864u) {   // Wcat1 = [hyp_Wx | hyp_Wh], (1024,1536)
        int n = (int)(i / 1536), k = (int)(i % 1536);
        float v = (k < 1280) ? hyp_Wx[(size_t)n*1280 + k] : hyp_Wh[(size_t)n*256 + (k-1280)];
        wcat1bf[i] = f2bf(v); return;
    }
    i -= 1572864u;
    if (i < 1048576u) { wxbf[i] = f2bf(Wx[i]); return; }
    i -= 1048576u;
    if (i < 4194304u) { whbf[i] = f2bf(Wh[i]); return; }
    i -= 4194304u;
    if (i < 1024u) { bias1[i] = hyp_bx[i] + hyp_bh[i]; return; }
    i -= 1024u;
    if (i < 163840u) { act1f[i] = 0.f; return; }
    i -= 163840u;
    if (i < 131072u) { c[i] = 0.f; return; }
    i -= 131072u;
    if (i < 32768u) { ch[i] = 0.f; return; }
    i -= 32768u;
    if (i < 81920u) { act1bf_zero[i] = 0u; return; }
    i -= 81920u;
    if (i < 512u) { gcnt_zero[i] = 0u; return; }
}
#define PREP_TOTAL 7226880u

__global__ __launch_bounds__(128) void k_prep_wcomb(
    const float* __restrict__ zw_w, const float* __restrict__ zb,
    const float* __restrict__ alpha, const float* __restrict__ zbeta,
    float* __restrict__ wcombf32)
{
    int kk = blockIdx.z;
    const float* A = (kk < 8) ? (zw_w + (size_t)kk*65536) : (zb + (size_t)(kk-8)*65536);
    const float* Bm = (kk < 8) ? (alpha + (size_t)kk*262144) : (zbeta + (size_t)(kk-8)*262144);
    gemm_dev(A, 256, KSPLIT_NONE, A, 256, Bm, 1024, 0, nullptr,
             wcombf32 + (size_t)kk*262144, 1024, 256, 0, blockIdx.x, blockIdx.y);
}

__global__ __launch_bounds__(256) void k_prep_cvtcomb(
    const float* __restrict__ wcombf32, unsigned short* __restrict__ wcombbf)
{
    size_t i = (size_t)blockIdx.x*256 + threadIdx.x;
    if (i >= 3145728u) return;
    int kk = (int)(i / 262144u);
    int r  = (int)(i % 262144u);
    int n = r / 256, k = r % 256;
    wcombbf[i] = f2bf(wcombf32[(size_t)kk*262144 + (size_t)k*1024 + n]);
}

__global__ __launch_bounds__(256) void k_prep_bcomb(
    const float* __restrict__ zw_b, const float* __restrict__ alpha,
    float* __restrict__ bcomb)
{
    int k = blockIdx.x;
    int n = blockIdx.y*256 + threadIdx.x;
    float s = 0.f;
    for (int p=0;p<256;++p)
        s += zw_b[k*256+p] * alpha[(size_t)k*262144 + (size_t)p*1024 + n];
    bcomb[(size_t)k*1024 + n] = s;
}

// =====================================================================
// reductions / cell bodies
// =====================================================================
__device__ __forceinline__ void breduce2(float& a, float& b, volatile float* buf, int tid){
    #pragma unroll
    for (int off = 32; off > 0; off >>= 1) { a += __shfl_xor(a, off); b += __shfl_xor(b, off); }
    __syncthreads();
    if ((tid & 63) == 0) { buf[(tid>>6)*2] = a; buf[(tid>>6)*2+1] = b; }
    __syncthreads();
    a = buf[0] + buf[2] + buf[4] + buf[6];
    b = buf[1] + buf[3] + buf[5] + buf[7];
}

// ---- coop-path cells: agent loads of partials, packed bf16 agent stores ----
__device__ __forceinline__ void hyper_cell6(
    int b, int tid, volatile float* cbuf,
    const float* __restrict__ gpart, const float* __restrict__ bias1,
    const float* __restrict__ lna_g, const float* __restrict__ lna_b,
    const float* __restrict__ ln_g, const float* __restrict__ ln_b,
    float* __restrict__ ch, unsigned short* __restrict__ act1bf)
{
    float v[4];
    #pragma unroll
    for (int g=0; g<4; ++g){
        size_t idx = (size_t)b*1024 + g*256 + tid;
        v[g] = agf(&gpart[idx]) + agf(&gpart[131072+idx]) + agf(&gpart[262144+idx])
             + agf(&gpart[393216+idx]) + agf(&gpart[524288+idx]) + agf(&gpart[655360+idx])
             + bias1[g*256 + tid];
    }
    #pragma unroll
    for (int g=0; g<4; ++g){
        float s = v[g], ss = v[g]*v[g];
        breduce2(s, ss, cbuf, tid);
        float m = s * (1.f/256.f);
        float var = ss * (1.f/256.f) - m*m;
        v[g] = (v[g]-m)*rsqrtf(var + EPS)*lna_g[g*256+tid] + lna_b[g*256+tid];
    }
    float chp = ch[b*256 + tid];
    float cn = sigm(v[1])*chp + sigm(v[0])*tanhf(v[2]);
    float s = cn, ss = cn*cn;
    breduce2(s, ss, cbuf, tid);
    float m = s*(1.f/256.f);
    float var = ss*(1.f/256.f) - m*m;
    float hn = sigm(v[3]) * tanhf((cn-m)*rsqrtf(var + EPS)*ln_g[tid] + ln_b[tid]);
    ch[b*256 + tid] = cn;
    // packed bf16 agent store (pairs of adjacent tids, same wave)
    unsigned hb = f2bf(hn);
    unsigned other = __shfl_down(hb, 1);
    if (!(tid & 1))
        agsu((unsigned*)(act1bf + (size_t)b*1280 + 1024 + tid), hb | (other << 16));
}

__device__ __forceinline__ void main_cell2(
    int b, int tid, volatile float* cbuf,
    const float* __restrict__ bias4,
    const float* __restrict__ lna_g, const float* __restrict__ lna_b,
    const float* __restrict__ ln_g, const float* __restrict__ ln_b,
    const float* __restrict__ xgbuf, const float* __restrict__ hgpart,
    const float* __restrict__ scb,
    float* __restrict__ c, unsigned short* __restrict__ act1bf,
    float* __restrict__ hfc)
{
    float gn[4][4];
    #pragma unroll
    for (int k=0;k<4;++k){
        float pre[4]; float s=0.f, ss=0.f;
        #pragma unroll
        for (int j=0;j<4;++j){
            int h = j*256 + tid;
            int n = k*1024 + h;
            size_t bh = (size_t)b*1024 + h;
            size_t bn = (size_t)b*4096 + n;
            float xgv = agf(&xgbuf[bn]);
            float hgv = agf(&hgpart[bn]) + agf(&hgpart[524288+bn])
                      + agf(&hgpart[1048576+bn]) + agf(&hgpart[1572864+bn]);
            float p = agf(&scb[(size_t)k*131072 + bh])*xgv
                    + agf(&scb[(size_t)(4+k)*131072 + bh])*hgv
                    + bias4[n] + agf(&scb[(size_t)(8+k)*131072 + bh]);
            pre[j] = p; s += p; ss += p*p;
        }
        breduce2(s, ss, cbuf, tid);
        float m = s*(1.f/1024.f);
        float var = ss*(1.f/1024.f) - m*m;
        float rs = rsqrtf(var + EPS);
        #pragma unroll
        for (int j=0;j<4;++j){
            int h=j*256+tid, n=k*1024+h;
            gn[k][j] = (pre[j]-m)*rs*lna_g[n] + lna_b[n];
        }
    }
    float cnv[4]; float s=0.f, ss=0.f;
    #pragma unroll
    for (int j=0;j<4;++j){
        int h=j*256+tid;
        float cv = c[(size_t)b*1024+h];
        float x = sigm(gn[2][j])*cv + sigm(gn[0][j])*tanhf(gn[1][j]);
        cnv[j]=x; s+=x; ss+=x*x;
    }
    breduce2(s, ss, cbuf, tid);
    float m=s*(1.f/1024.f);
    float var=ss*(1.f/1024.f)-m*m;
    float rs=rsqrtf(var + EPS);
    #pragma unroll
    for (int j=0;j<4;++j){
        int h=j*256+tid;
        float hv = sigm(gn[3][j])*tanhf((cnv[j]-m)*rs*ln_g[h] + ln_b[h]);
        c[(size_t)b*1024+h] = cnv[j];
        hfc[(size_t)b*1024 + h] = hv;
        unsigned hb = f2bf(hv);
        unsigned other = __shfl_down(hb, 1);
        if (!(tid & 1))
            agsu((unsigned*)(act1bf + (size_t)b*1280 + h), hb | (other << 16));
    }
}

// ---- fallback cells (f32 activations, 4-way gpart) ----
__device__ __forceinline__ void hyper_cell_body(
    const float* __restrict__ lna_g, const float* __restrict__ lna_b,
    const float* __restrict__ ln_g, const float* __restrict__ ln_b,
    const float* __restrict__ gpart, const float* __restrict__ bias1,
    float* __restrict__ ch, float* __restrict__ act1, int b, int tid)
{
    __shared__ float buf[8];
    float v[4];
    #pragma unroll
    for (int g=0; g<4; ++g){
        int idx = b*1024 + g*256 + tid;
        v[g] = gpart[idx] + gpart[131072 + idx] + gpart[262144 + idx] + gpart[393216 + idx]
             + bias1[g*256 + tid];
    }
    #pragma unroll
    for (int g=0; g<4; ++g){
        float s = v[g], ss = v[g]*v[g];
        breduce2(s, ss, buf, tid);
        float m = s * (1.f/256.f);
        float var = ss * (1.f/256.f) - m*m;
        v[g] = (v[g]-m)*rsqrtf(var + EPS)*lna_g[g*256+tid] + lna_b[g*256+tid];
    }
    float chp = ch[b*256 + tid];
    float cn = sigm(v[1])*chp + sigm(v[0])*tanhf(v[2]);
    float s = cn, ss = cn*cn;
    breduce2(s, ss, buf, tid);
    float m = s*(1.f/256.f);
    float var = ss*(1.f/256.f) - m*m;
    float hn = sigm(v[3]) * tanhf((cn-m)*rsqrtf(var + EPS)*ln_g[tid] + ln_b[tid]);
    ch[b*256 + tid] = cn;
    act1[b*1280 + 1024 + tid] = hn;
}

__device__ __forceinline__ void main_cell_body(
    const float* __restrict__ bias4,
    const float* __restrict__ lna_g, const float* __restrict__ lna_b,
    const float* __restrict__ ln_g, const float* __restrict__ ln_b,
    const float* __restrict__ xghg, const float* __restrict__ scb,
    float* __restrict__ c, float* __restrict__ act1, int b, int tid)
{
    __shared__ float buf[8];
    float gn[4][4];
    #pragma unroll
    for (int k=0;k<4;++k){
        float pre[4]; float s=0.f, ss=0.f;
        #pragma unroll
        for (int j=0;j<4;++j){
            int h = j*256 + tid;
            int n = k*1024 + h;
            int bh = b*1024 + h;
            float xgv = xghg[b*4096 + n];
            float hgv = xghg[524288 + b*4096 + n];
            float p = scb[k*131072 + bh]*xgv + scb[(4+k)*131072 + bh]*hgv
                    + bias4[n] + scb[(8+k)*131072 + bh];
            pre[j] = p; s += p; ss += p*p;
        }
        breduce2(s, ss, buf, tid);
        float m = s*(1.f/1024.f);
        float var = ss*(1.f/1024.f) - m*m;
        float rs = rsqrtf(var + EPS);
        #pragma unroll
        for (int j=0;j<4;++j){
            int h=j*256+tid, n=k*1024+h;
            gn[k][j] = (pre[j]-m)*rs*lna_g[n] + lna_b[n];
        }
    }
    float cnv[4]; float s=0.f, ss=0.f;
    #pragma unroll
    for (int j=0;j<4;++j){
        int h=j*256+tid;
        float cv = c[b*1024+h];
        float x = sigm(gn[2][j])*cv + sigm(gn[0][j])*tanhf(gn[1][j]);
        cnv[j]=x; s+=x; ss+=x*x;
    }
    breduce2(s, ss, buf, tid);
    float m=s*(1.f/1024.f);
    float var=ss*(1.f/1024.f)-m*m;
    float rs=rsqrtf(var + EPS);
    #pragma unroll
    for (int j=0;j<4;++j){
        int h=j*256+tid;
        float hv = sigm(gn[3][j])*tanhf((cnv[j]-m)*rs*ln_g[h] + ln_b[h]);
        c[b*1024+h] = cnv[j];
        act1[b*1280 + h] = hv;
    }
}

// =====================================================================
// fallback step kernels
// =====================================================================
__global__ __launch_bounds__(256) void k_step1(
    const float* __restrict__ xt, const float* __restrict__ act1,
    const unsigned short* __restrict__ wcat1bf,
    const unsigned short* __restrict__ wxbf, const unsigned short* __restrict__ whbf,
    float* __restrict__ gpart, float* __restrict__ xghg)
{
    int bid = blockIdx.x;
    if (bid < 128) {
        int sp = bid >> 5, r = bid & 31;
        gemm_mfma(xt, 256, 256, act1, 1280, wcat1bf, 1536, nullptr,
                  gpart + (size_t)sp*131072, 1024, 384, sp*384, r >> 3, r & 7);
    } else if (bid < 256) {
        int r = bid - 128;
        gemm_mfma(xt, 256, KSPLIT_NONE, xt, 256, wxbf, 256, nullptr,
                  xghg, 4096, 256, 0, r >> 5, r & 31);
    } else {
        int r = bid - 256;
        gemm_mfma(act1, 1280, KSPLIT_NONE, act1, 1280, whbf, 1024, nullptr,
                  xghg + 524288, 4096, 1024, 0, r >> 5, r & 31);
    }
}

__global__ __launch_bounds__(256) void k_step2(
    const float* __restrict__ act1, const unsigned short* __restrict__ wcombbf,
    const float* __restrict__ bcomb, float* __restrict__ scb)
{
    int bid = blockIdx.x;
    int kk = bid >> 5, r = bid & 31;
    const float* bias = (kk < 8) ? (bcomb + (size_t)kk*1024) : nullptr;
    gemm_mfma(act1 + 1024, 1280, KSPLIT_NONE, act1 + 1024, 1280,
              wcombbf + (size_t)kk*262144, 256, bias,
              scb + (size_t)kk*131072, 1024, 256, 0, r >> 3, r & 7);
}

__global__ __launch_bounds__(256) void k_hyper_cell(
    const float* __restrict__ lna_g, const float* __restrict__ lna_b,
    const float* __restrict__ ln_g, const float* __restrict__ ln_b,
    const float* __restrict__ gpart, const float* __restrict__ bias1,
    float* __restrict__ ch, float* __restrict__ act1)
{
    hyper_cell_body(lna_g, lna_b, ln_g, ln_b, gpart, bias1, ch, act1,
                    blockIdx.x, threadIdx.x);
}

__global__ __launch_bounds__(256) void k_main_cell(
    const float* __restrict__ bias4,
    const float* __restrict__ lna_g, const float* __restrict__ lna_b,
    const float* __restrict__ ln_g, const float* __restrict__ ln_b,
    const float* __restrict__ xghg, const float* __restrict__ scb,
    float* __restrict__ c, float* __restrict__ act1)
{
    main_cell_body(bias4, lna_g, lna_b, ln_g, ln_b, xghg, scb, c, act1,
                   blockIdx.x, threadIdx.x);
}

// =====================================================================
// persistent kernel v4: weights in LDS + fence-free agent-scope phases.
// REGULAR (non-cooperative) launch: graph-capturable. Co-residency is
// guaranteed by __launch_bounds__(256,2): 2 blocks/CU x 256 CU = 512.
// =====================================================================
__global__ __launch_bounds__(256, 2) void k_persist4(
    const float* __restrict__ x,
    const unsigned short* __restrict__ wcat1bf,
    const unsigned short* __restrict__ wxbf,
    const unsigned short* __restrict__ whbf,
    const unsigned short* __restrict__ wcombbf,
    const float* __restrict__ bcomb, const float* __restrict__ bias1,
    const float* __restrict__ bias4,
    const float* __restrict__ lna_g, const float* __restrict__ lna_b,
    const float* __restrict__ ln_g, const float* __restrict__ ln_b,
    const float* __restrict__ hlna_g, const float* __restrict__ hlna_b,
    const float* __restrict__ hln_g, const float* __restrict__ hln_b,
    float* __restrict__ gpart, float* __restrict__ hgpart,
    float* __restrict__ xgbuf, float* __restrict__ scb,
    unsigned short* __restrict__ act1bf, float* __restrict__ hfc,
    float* __restrict__ c, float* __restrict__ ch,
    unsigned* __restrict__ gcnt)
{
    const int bid = blockIdx.x, tid = threadIdx.x;
    const int lane = tid & 63, w = tid >> 6;
    __shared__ __align__(16) unsigned short wlds[25344];  // [64][264] + [32][264]
    __shared__ float cbuf[8];

    // ---- one-time weight preload into LDS ----
    if (bid < 96) {
        load_wtile(wcat1bf + (size_t)((bid & 15)*64)*1536 + (bid >> 4)*256,
                   1536, wlds, 64, tid);
    } else if (bid < 352) {
        int h_ = bid - 96;
        load_wtile(whbf + (size_t)((h_ >> 2)*64)*1024 + (h_ & 3)*256,
                   1024, wlds, 64, tid);
    } else if (bid < 416) {
        load_wtile(wxbf + (size_t)(bid - 352)*64*256, 256, wlds, 64, tid);
    }
    if (bid < 384) {
        int kk = bid >> 5, mt = bid & 31;
        load_wtile(wcombbf + (size_t)kk*262144 + (size_t)(mt*32)*256,
                   256, wlds + 16896, 32, tid);
    }
    __syncthreads();

    unsigned phase = 0;
    for (int t = 0; t < T_STEPS; ++t) {
        const float* xt = x + (size_t)t*BATCH*DIN;

        // ---- phase A: hyper gates g1 (6 pure K-splits) ----
        if (bid < 96) {
            int nt = bid & 15, sp = bid >> 4;
            float* outp = gpart + (size_t)sp*131072 + nt*64;
            if (sp == 0)
                gemm_ws<4,0>(xt, 256, wlds, nullptr, outp, 1024, lane, w);
            else
                gemm_ws<4,2>(act1bf + (sp-1)*256, 1280, wlds, nullptr, outp, 1024, lane, w);
        }
        gbar(gcnt, ++phase, bid, tid);

        // ---- phase B: hg (split-K4) + xg + hyper cell ----
        if (bid >= 96 && bid < 352) {
            int h_ = bid - 96, nt = h_ >> 2, sp = h_ & 3;
            gemm_ws<4,2>(act1bf + sp*256, 1280, wlds, nullptr,
                         hgpart + (size_t)sp*524288 + nt*64, 4096, lane, w);
        } else if (bid >= 352 && bid < 416) {
            gemm_ws<4,0>(xt, 256, wlds, nullptr,
                         xgbuf + (bid - 352)*64, 4096, lane, w);
        } else {
            int row = (bid >= 416) ? (bid - 416) : (bid < 32 ? 96 + bid : -1);
            if (row >= 0)
                hyper_cell6(row, tid, cbuf, gpart, bias1,
                            hlna_g, hlna_b, hln_g, hln_b, ch, act1bf);
        }
        gbar(gcnt, ++phase, bid, tid);

        // ---- phase C: 12 x (hyp @ Wcomb[k]) ----
        if (bid < 384) {
            int kk = bid >> 5, mt = bid & 31;
            const float* bp = (kk < 8) ? (bcomb + (size_t)kk*1024 + mt*32) : nullptr;
            gemm_ws<2,2>(act1bf + 1024, 1280, wlds + 16896, bp,
                         scb + (size_t)kk*131072 + mt*32, 1024, lane, w);
        }
        gbar(gcnt, ++phase, bid, tid);

        // ---- phase D: main cell ----
        if (bid < 128)
            main_cell2(bid, tid, cbuf, bias4, lna_g, lna_b, ln_g, ln_b,
                       xgbuf, hgpart, scb, c, act1bf, hfc);
        gbar(gcnt, ++phase, bid, tid);
    }
}

__global__ __launch_bounds__(128) void k_fc2(
    const float* __restrict__ fcW, const float* __restrict__ fcb,
    const float* __restrict__ hsrc, int ldh, float* __restrict__ out)
{
    int b = blockIdx.x, o = threadIdx.x;
    const float* h = hsrc + (size_t)b*ldh;
    float s = fcb[o];
    for (int k=0;k<1024;++k) s += h[k]*fcW[(size_t)o*1024 + k];
    out[b*OUTN + o] = s;
}

// =====================================================================
// launch
// =====================================================================
extern "C" void kernel_launch(void* const* d_in, const int* in_sizes, int n_in,
                              void* d_out, int out_size, void* d_ws, size_t ws_size,
                              hipStream_t stream)
{
    const float* x        = (const float*)d_in[0];
    const float* Wx       = (const float*)d_in[1];
    const float* Wh       = (const float*)d_in[2];
    const float* bias     = (const float*)d_in[3];
    const float* lna_g    = (const float*)d_in[4];
    const float* lna_b    = (const float*)d_in[5];
    const float* ln_g     = (const float*)d_in[6];
    const float* ln_b     = (const float*)d_in[7];
    const float* zb       = (const float*)d_in[8];
    const float* zbeta    = (const float*)d_in[9];
    const float* zw_w     = (const float*)d_in[10];
    const float* zw_b     = (const float*)d_in[11];
    const float* alpha    = (const float*)d_in[12];
    const float* hyp_Wx   = (const float*)d_in[13];
    const float* hyp_bx   = (const float*)d_in[14];
    const float* hyp_Wh   = (const float*)d_in[15];
    const float* hyp_bh   = (const float*)d_in[16];
    const float* hlna_g   = (const float*)d_in[17];
    const float* hlna_b   = (const float*)d_in[18];
    const float* hln_g    = (const float*)d_in[19];
    const float* hln_b    = (const float*)d_in[20];
    const float* fcW      = (const float*)d_in[21];
    const float* fcb      = (const float*)d_in[22];
    float* out = (float*)d_out;

    // ---- workspace carve (elements) ----
    unsigned short* wcat1bf = (unsigned short*)d_ws;          // 1572864
    unsigned short* wxbf    = wcat1bf + 1572864;              // 1048576
    unsigned short* whbf    = wxbf + 1048576;                 // 4194304
    unsigned short* wcombbf = whbf + 4194304;                 // 3145728
    unsigned short* act1bf  = wcombbf + 3145728;              // 163840 (bf16 [h|hh])
    float* fbase = (float*)(act1bf + 163840);
    float* bcomb = fbase;                                     // 8192
    float* bias1 = bcomb + 8192;                              // 1024
    float* hfc   = bias1 + 1024;                              // 131072 (f32 h for fc)
    float* c     = hfc + 131072;                              // 131072
    float* ch    = c + 131072;                                // 32768
    float* act1o = ch + 32768;                                // 163840 (f32, fallback)
    float* gpart = act1o + 163840;                            // 786432 (6 x 131072)
    float* hgpart= gpart + 786432;                            // 2097152 (4 x 524288)
    float* xgbuf = hgpart + 2097152;                          // 524288
    float* scb   = xgbuf + 524288;                            // 1572864 (12 x 131072)
    unsigned* gcnt = (unsigned*)(scb + 1572864);              // 512 uints (16 lines)
    float* wcombf32 = gpart;                                  // prep-time alias

    // ---- prep ----
    k_prep_convert<<<(PREP_TOTAL + 255)/256, 256, 0, stream>>>(
        hyp_Wx, hyp_Wh, hyp_bx, hyp_bh, Wx, Wh,
        wcat1bf, wxbf, whbf, bias1, act1o, c, ch,
        (unsigned int*)act1bf, gcnt);
    k_prep_wcomb<<<dim3(8,16,12), 128, 0, stream>>>(zw_w, zb, alpha, zbeta, wcombf32);
    k_prep_bcomb<<<dim3(8,4), 256, 0, stream>>>(zw_b, alpha, bcomb);
    k_prep_cvtcomb<<<(3145728 + 255)/256, 256, 0, stream>>>(wcombf32, wcombbf);

    // ---- capability gate (host-side queries only; capture-safe) ----
    // Persistent path needs all 512 blocks co-resident: occ>=2 blocks/CU
    // and >=256 CUs. Verified via occupancy API once, cached.
    static int use_pers = -1;
    if (use_pers < 0) {
        use_pers = 0;
        int dev = 0;
        if (hipGetDevice(&dev) == hipSuccess) {
            hipDeviceProp_t prop;
            if (hipGetDeviceProperties(&prop, dev) == hipSuccess) {
                int occ = 0;
                if (hipOccupancyMaxActiveBlocksPerMultiprocessor(
                        &occ, (const void*)k_persist4, 256, 0) == hipSuccess &&
                    occ >= 2 && occ * prop.multiProcessorCount >= NBLK) {
                    use_pers = 1;
                }
            }
        }
    }

    if (use_pers) {
        // REGULAR launch — graph-capturable, unlike hipLaunchCooperativeKernel.
        k_persist4<<<NBLK, 256, 0, stream>>>(
            x, wcat1bf, wxbf, whbf, wcombbf,
            bcomb, bias1, bias,
            lna_g, lna_b, ln_g, ln_b,
            hlna_g, hlna_b, hln_g, hln_b,
            gpart, hgpart, xgbuf, scb,
            act1bf, hfc, c, ch, gcnt);
        k_fc2<<<BATCH, 128, 0, stream>>>(fcW, fcb, hfc, 1024, out);
        return;
    }

    // ---- fallback: old 4-launch structure ----
    float* xghg = hgpart;
    for (int t = 0; t < T_STEPS; ++t) {
        const float* xt = x + (size_t)t*BATCH*DIN;
        k_step1<<<384, 256, 0, stream>>>(xt, act1o, wcat1bf, wxbf, whbf, gpart, xghg);
        k_hyper_cell<<<BATCH, 256, 0, stream>>>(hlna_g, hlna_b, hln_g, hln_b,
                                                gpart, bias1, ch, act1o);
        k_step2<<<384, 256, 0, stream>>>(act1o, wcombbf, bcomb, scb);
        k_main_cell<<<BATCH, 256, 0, stream>>>(bias, lna_g, lna_b, ln_g, ln_b,
                                               xghg, scb, c, act1o);
    }
    k_fc2<<<BATCH, 128, 0, stream>>>(fcW, fcb, act1o, 1280, out);
}